// Round 2
// baseline (12566.843 us; speedup 1.0000x reference)
//
#include <hip/hip_runtime.h>
#include <hip/hip_bf16.h>

// Problem constants (from setup_inputs)
#define BB   64      // batch
#define SS   256     // src sequence (16*16)
#define DD   512     // model dim
#define DFF  2048
#define DIN  256
#define NH   8
#define DH   64
#define TLEN 16      // description_length (fixed by setup)
#define TCAP 17      // tgt capacity (start token + 16)

constexpr size_t AREG = (size_t)BB * SS * DD;   // 8,388,608 floats per [B,S,D] buffer
constexpr int    BH17 = BB * NH * TCAP * DH;    // 557,056

// ---------------------------------------------------------------------------
// Generic fp32 GEMM: C[M,N] = A[M,K] @ W[N,K]^T + bias, with epilogue modes.
// mode 0: plain   -> out[row*N + col]
// mode 1: relu    -> out[row*N + col]
// mode 2: qkv / mem-kv head scatter: out[which*AREG + ((b*8+h)*256+s)*64+d]
// mode 4: dec qkv: q -> out[b*512+col], k/v -> aux[(which-1)*BH17+((b*8+h)*17+p1)*64+d]
// Requirements: K % 16 == 0, N % 128 == 0. M guarded.
// 128x128x16 tile, 256 threads, 8x8 per-thread accumulator.
// ---------------------------------------------------------------------------
#define BM 128
#define BN 128
#define BK 16

__global__ __launch_bounds__(256) void gemm_k(
    const float* __restrict__ A, int lda,
    const float* __restrict__ W,
    const float* __restrict__ bias,
    float* __restrict__ out, float* __restrict__ aux,
    int M, int N, int K, int mode, int p1)
{
    __shared__ float sA[BK][BM + 4];
    __shared__ float sB[BK][BN + 4];

    const int row0 = blockIdx.x * BM;
    const int col0 = blockIdx.y * BN;
    const int tid  = threadIdx.x;
    const int tx   = tid & 15;        // N dir, 8 cols each
    const int ty   = tid >> 4;        // M dir, 8 rows each

    float acc[8][8];
    #pragma unroll
    for (int i = 0; i < 8; ++i)
        #pragma unroll
        for (int j = 0; j < 8; ++j) acc[i][j] = 0.f;

    const int ar  = tid >> 2;          // 0..63
    const int ac4 = (tid & 3) * 4;     // 0,4,8,12

    for (int k0 = 0; k0 < K; k0 += BK) {
        // stage A tile (128 rows x 16 k), transposed into sA[k][m]; M-guarded
        #pragma unroll
        for (int i = 0; i < 2; ++i) {
            int r = ar + i * 64;
            int grow = row0 + r;
            float4 v = make_float4(0.f, 0.f, 0.f, 0.f);
            if (grow < M) v = *(const float4*)&A[(long)grow * lda + k0 + ac4];
            sA[ac4 + 0][r] = v.x; sA[ac4 + 1][r] = v.y;
            sA[ac4 + 2][r] = v.z; sA[ac4 + 3][r] = v.w;
        }
        // stage W tile (128 cols x 16 k), transposed into sB[k][n]
        #pragma unroll
        for (int i = 0; i < 2; ++i) {
            int c = ar + i * 64;
            float4 v = *(const float4*)&W[(long)(col0 + c) * K + k0 + ac4];
            sB[ac4 + 0][c] = v.x; sB[ac4 + 1][c] = v.y;
            sB[ac4 + 2][c] = v.z; sB[ac4 + 3][c] = v.w;
        }
        __syncthreads();

        #pragma unroll
        for (int k = 0; k < BK; ++k) {
            float4 a0 = *(const float4*)&sA[k][ty * 8];
            float4 a1 = *(const float4*)&sA[k][ty * 8 + 4];
            float4 b0 = *(const float4*)&sB[k][tx * 8];
            float4 b1 = *(const float4*)&sB[k][tx * 8 + 4];
            float a[8] = {a0.x, a0.y, a0.z, a0.w, a1.x, a1.y, a1.z, a1.w};
            float b[8] = {b0.x, b0.y, b0.z, b0.w, b1.x, b1.y, b1.z, b1.w};
            #pragma unroll
            for (int i = 0; i < 8; ++i)
                #pragma unroll
                for (int j = 0; j < 8; ++j)
                    acc[i][j] = fmaf(a[i], b[j], acc[i][j]);
        }
        __syncthreads();
    }

    // epilogue
    const int gcol0 = col0 + tx * 8;
    float4 bb0 = *(const float4*)&bias[gcol0];
    float4 bb1 = *(const float4*)&bias[gcol0 + 4];
    float bs[8] = {bb0.x, bb0.y, bb0.z, bb0.w, bb1.x, bb1.y, bb1.z, bb1.w};
    #pragma unroll
    for (int i = 0; i < 8; ++i) {
        int grow = row0 + ty * 8 + i;
        if (grow >= M) continue;
        float v[8];
        #pragma unroll
        for (int j = 0; j < 8; ++j) {
            v[j] = acc[i][j] + bs[j];
            if (mode == 1) v[j] = fmaxf(v[j], 0.f);
        }
        float4 v0 = make_float4(v[0], v[1], v[2], v[3]);
        float4 v1 = make_float4(v[4], v[5], v[6], v[7]);
        if (mode <= 1) {
            float* p = &out[(long)grow * N + gcol0];
            *(float4*)p = v0; *(float4*)(p + 4) = v1;
        } else if (mode == 2) {
            int b = grow >> 8, s = grow & 255;
            int which = gcol0 >> 9;                    // 512-col chunk: q/k/v
            int h = (gcol0 >> 6) & 7, d = gcol0 & 63;  // 8 cols stay in one head
            float* p = &out[(long)which * AREG + (((b * 8 + h) * 256 + s) * 64 + d)];
            *(float4*)p = v0; *(float4*)(p + 4) = v1;
        } else { // mode 4
            int b = grow;
            int which = gcol0 >> 9;
            if (which == 0) {
                float* p = &out[b * 512 + gcol0];
                *(float4*)p = v0; *(float4*)(p + 4) = v1;
            } else {
                int h = (gcol0 >> 6) & 7, d = gcol0 & 63;
                float* p = &aux[(long)(which - 1) * BH17 + ((b * 8 + h) * TCAP + p1) * 64 + d];
                *(float4*)p = v0; *(float4*)(p + 4) = v1;
            }
        }
    }
}

// ---------------------------------------------------------------------------
// Encoder fused attention: one block (256 thr) per (b,h); thread = 1 q row.
// q,k,v laid out [B,H,S,DH]. out: [B,S,D] with head-concat.
// ---------------------------------------------------------------------------
__global__ __launch_bounds__(256) void enc_attn_k(
    const float* __restrict__ q, const float* __restrict__ k,
    const float* __restrict__ v, float* __restrict__ out)
{
    const int bh = blockIdx.x;
    const int b = bh >> 3, h = bh & 7;
    const float* Q = q + (long)bh * SS * DH;
    const float* Kp = k + (long)bh * SS * DH;
    const float* Vp = v + (long)bh * SS * DH;
    const int t = threadIdx.x;

    __shared__ float4 sK[16][16];
    __shared__ float4 sV[16][16];

    float4 q4[16];
    #pragma unroll
    for (int i = 0; i < 16; ++i) q4[i] = *(const float4*)&Q[t * 64 + i * 4];

    float4 o4[16];
    #pragma unroll
    for (int i = 0; i < 16; ++i) o4[i] = make_float4(0.f, 0.f, 0.f, 0.f);
    float m = -1e30f, l = 0.f;

    const int r = t >> 4, c4 = t & 15;
    for (int c = 0; c < 16; ++c) {
        sK[r][c4] = *(const float4*)&Kp[(c * 16 + r) * 64 + c4 * 4];
        sV[r][c4] = *(const float4*)&Vp[(c * 16 + r) * 64 + c4 * 4];
        __syncthreads();

        float sc[16];
        #pragma unroll
        for (int kk = 0; kk < 16; ++kk) {
            float s = 0.f;
            #pragma unroll
            for (int i = 0; i < 16; ++i) {
                float4 kv = sK[kk][i];
                s = fmaf(q4[i].x, kv.x, s); s = fmaf(q4[i].y, kv.y, s);
                s = fmaf(q4[i].z, kv.z, s); s = fmaf(q4[i].w, kv.w, s);
            }
            sc[kk] = s * 0.125f;
        }
        float cm = sc[0];
        #pragma unroll
        for (int kk = 1; kk < 16; ++kk) cm = fmaxf(cm, sc[kk]);
        float mn = fmaxf(m, cm);
        float alpha = __expf(m - mn);
        float ps[16]; float psum = 0.f;
        #pragma unroll
        for (int kk = 0; kk < 16; ++kk) { ps[kk] = __expf(sc[kk] - mn); psum += ps[kk]; }
        l = l * alpha + psum;
        #pragma unroll
        for (int i = 0; i < 16; ++i) {
            o4[i].x *= alpha; o4[i].y *= alpha; o4[i].z *= alpha; o4[i].w *= alpha;
        }
        #pragma unroll
        for (int kk = 0; kk < 16; ++kk) {
            float p = ps[kk];
            #pragma unroll
            for (int i = 0; i < 16; ++i) {
                float4 vv = sV[kk][i];
                o4[i].x = fmaf(p, vv.x, o4[i].x); o4[i].y = fmaf(p, vv.y, o4[i].y);
                o4[i].z = fmaf(p, vv.z, o4[i].z); o4[i].w = fmaf(p, vv.w, o4[i].w);
            }
        }
        m = mn;
        __syncthreads();
    }

    float inv = 1.f / l;
    float* O = out + ((long)(b * SS + t)) * DD + h * DH;
    #pragma unroll
    for (int i = 0; i < 16; ++i) {
        float4 v_;
        v_.x = o4[i].x * inv; v_.y = o4[i].y * inv;
        v_.z = o4[i].z * inv; v_.w = o4[i].w * inv;
        *(float4*)&O[i * 4] = v_;
    }
}

// ---------------------------------------------------------------------------
// Decode self-attention with KV cache. 1 wave per (b,h). L = t+1 keys.
// ---------------------------------------------------------------------------
__global__ __launch_bounds__(64) void dec_sa_k(
    const float* __restrict__ qbuf, const float* __restrict__ kc,
    const float* __restrict__ vc, float* __restrict__ out, int t)
{
    const int bh = blockIdx.x;
    const int b = bh >> 3, h = bh & 7;
    const int lane = threadIdx.x;
    const int L = t + 1;

    __shared__ float sq[64];
    __shared__ float sp[64];

    sq[lane] = qbuf[b * DD + h * DH + lane];
    __syncthreads();

    const float* K = kc + (long)bh * TCAP * DH;
    float s = -1e30f;
    if (lane < L) {
        float acc = 0.f;
        #pragma unroll
        for (int d = 0; d < 64; d += 4) {
            float4 kr = *(const float4*)&K[lane * 64 + d];
            acc = fmaf(sq[d], kr.x, acc); acc = fmaf(sq[d + 1], kr.y, acc);
            acc = fmaf(sq[d + 2], kr.z, acc); acc = fmaf(sq[d + 3], kr.w, acc);
        }
        s = acc * 0.125f;
    }
    float mx = s;
    #pragma unroll
    for (int off = 32; off; off >>= 1) mx = fmaxf(mx, __shfl_xor(mx, off));
    float p = (lane < L) ? __expf(s - mx) : 0.f;
    float sum = p;
    #pragma unroll
    for (int off = 32; off; off >>= 1) sum += __shfl_xor(sum, off);
    sp[lane] = p;
    __syncthreads();

    const float* V = vc + (long)bh * TCAP * DH;
    float o = 0.f;
    for (int kk = 0; kk < L; ++kk) o = fmaf(sp[kk], V[kk * 64 + lane], o);
    out[b * DD + h * DH + lane] = o / sum;
}

// ---------------------------------------------------------------------------
// Decode cross-attention over mem (256 keys). 256 threads per (b,h).
// ---------------------------------------------------------------------------
__global__ __launch_bounds__(256) void dec_ca_k(
    const float* __restrict__ caq, const float* __restrict__ mk,
    const float* __restrict__ mv, float* __restrict__ out)
{
    const int bh = blockIdx.x;
    const int b = bh >> 3, h = bh & 7;
    const int tid = threadIdx.x;

    __shared__ float sq[64];
    __shared__ float sp[256];
    __shared__ float red[8];
    __shared__ float so[4][64];

    if (tid < 64) sq[tid] = caq[b * DD + h * DH + tid];
    __syncthreads();

    const float* K = mk + (long)bh * SS * DH;
    float acc = 0.f;
    #pragma unroll
    for (int d = 0; d < 64; d += 4) {
        float4 kr = *(const float4*)&K[tid * 64 + d];
        acc = fmaf(sq[d], kr.x, acc); acc = fmaf(sq[d + 1], kr.y, acc);
        acc = fmaf(sq[d + 2], kr.z, acc); acc = fmaf(sq[d + 3], kr.w, acc);
    }
    float s = acc * 0.125f;

    float mx = s;
    #pragma unroll
    for (int off = 32; off; off >>= 1) mx = fmaxf(mx, __shfl_xor(mx, off));
    const int w = tid >> 6;
    if ((tid & 63) == 0) red[w] = mx;
    __syncthreads();
    mx = fmaxf(fmaxf(red[0], red[1]), fmaxf(red[2], red[3]));

    float p = __expf(s - mx);
    sp[tid] = p;
    float sum = p;
    #pragma unroll
    for (int off = 32; off; off >>= 1) sum += __shfl_xor(sum, off);
    if ((tid & 63) == 0) red[4 + w] = sum;
    __syncthreads();
    sum = red[4] + red[5] + red[6] + red[7];

    const float* V = mv + (long)bh * SS * DH;
    const int d = tid & 63;
    float o = 0.f;
    for (int kk = 0; kk < 64; ++kk) {
        int krow = w * 64 + kk;
        o = fmaf(sp[krow], V[krow * 64 + d], o);
    }
    so[w][d] = o;
    __syncthreads();
    if (tid < 64) {
        float rslt = (so[0][tid] + so[1][tid] + so[2][tid] + so[3][tid]) / sum;
        out[b * DD + h * DH + tid] = rslt;
    }
}

// ---------------------------------------------------------------------------
// LayerNorm, wave per row, D=512. out = LN(x + r); dbl=1: out = LN2(LN1(x+r)).
// ---------------------------------------------------------------------------
__global__ __launch_bounds__(256) void ln_k(
    const float* __restrict__ x, long xs,
    const float* __restrict__ r, long rs,
    const float* __restrict__ g1, const float* __restrict__ b1,
    const float* __restrict__ g2, const float* __restrict__ b2,
    float* __restrict__ out, long os, int nrows, int dbl)
{
    const int row = blockIdx.x * 4 + (threadIdx.x >> 6);
    if (row >= nrows) return;
    const int lane = threadIdx.x & 63;

    const float* X = x + (long)row * xs;
    const float* R = r + (long)row * rs;
    float y[8];
    {
        float4 a = *(const float4*)&X[lane * 4];
        float4 c = *(const float4*)&X[256 + lane * 4];
        float4 ra = *(const float4*)&R[lane * 4];
        float4 rc = *(const float4*)&R[256 + lane * 4];
        y[0] = a.x + ra.x; y[1] = a.y + ra.y; y[2] = a.z + ra.z; y[3] = a.w + ra.w;
        y[4] = c.x + rc.x; y[5] = c.y + rc.y; y[6] = c.z + rc.z; y[7] = c.w + rc.w;
    }
    float sum = 0.f, sq = 0.f;
    #pragma unroll
    for (int i = 0; i < 8; ++i) { sum += y[i]; sq = fmaf(y[i], y[i], sq); }
    #pragma unroll
    for (int off = 32; off; off >>= 1) {
        sum += __shfl_xor(sum, off);
        sq  += __shfl_xor(sq, off);
    }
    float mean = sum * (1.f / 512.f);
    float var  = sq * (1.f / 512.f) - mean * mean;
    float rstd = rsqrtf(var + 1e-5f);
    {
        float4 ga = *(const float4*)&g1[lane * 4];
        float4 gc = *(const float4*)&g1[256 + lane * 4];
        float4 ba = *(const float4*)&b1[lane * 4];
        float4 bc = *(const float4*)&b1[256 + lane * 4];
        float gs[8] = {ga.x, ga.y, ga.z, ga.w, gc.x, gc.y, gc.z, gc.w};
        float bs[8] = {ba.x, ba.y, ba.z, ba.w, bc.x, bc.y, bc.z, bc.w};
        #pragma unroll
        for (int i = 0; i < 8; ++i) y[i] = fmaf((y[i] - mean) * rstd, gs[i], bs[i]);
    }
    if (dbl) {
        float sum2 = 0.f, sq2 = 0.f;
        #pragma unroll
        for (int i = 0; i < 8; ++i) { sum2 += y[i]; sq2 = fmaf(y[i], y[i], sq2); }
        #pragma unroll
        for (int off = 32; off; off >>= 1) {
            sum2 += __shfl_xor(sum2, off);
            sq2  += __shfl_xor(sq2, off);
        }
        float mean2 = sum2 * (1.f / 512.f);
        float var2  = sq2 * (1.f / 512.f) - mean2 * mean2;
        float rstd2 = rsqrtf(var2 + 1e-5f);
        float4 ga = *(const float4*)&g2[lane * 4];
        float4 gc = *(const float4*)&g2[256 + lane * 4];
        float4 ba = *(const float4*)&b2[lane * 4];
        float4 bc = *(const float4*)&b2[256 + lane * 4];
        float gs[8] = {ga.x, ga.y, ga.z, ga.w, gc.x, gc.y, gc.z, gc.w};
        float bs[8] = {ba.x, ba.y, ba.z, ba.w, bc.x, bc.y, bc.z, bc.w};
        #pragma unroll
        for (int i = 0; i < 8; ++i) y[i] = fmaf((y[i] - mean2) * rstd2, gs[i], bs[i]);
    }
    float* O = out + (long)row * os;
    float4 w0 = make_float4(y[0], y[1], y[2], y[3]);
    float4 w1 = make_float4(y[4], y[5], y[6], y[7]);
    *(float4*)&O[lane * 4] = w0;
    *(float4*)&O[256 + lane * 4] = w1;
}

// ---------------------------------------------------------------------------
// tgt[:,0,:] = start_token
// ---------------------------------------------------------------------------
__global__ __launch_bounds__(256) void init_tgt_k(
    const float* __restrict__ start, float* __restrict__ tgt)
{
    int idx = blockIdx.x * 256 + threadIdx.x;  // over 64*512
    if (idx >= BB * DD) return;
    int b = idx >> 9, d = idx & 511;
    tgt[(long)b * TCAP * DD + d] = start[d];
}

// ---------------------------------------------------------------------------
// packed[b*16+s][d] = tgt[b][s+1][d]
// ---------------------------------------------------------------------------
__global__ __launch_bounds__(256) void pack_k(
    const float* __restrict__ tgt, float* __restrict__ packed)
{
    int idx = blockIdx.x * 256 + threadIdx.x;  // over 1024*512
    if (idx >= BB * TLEN * DD) return;
    int d = idx & 511;
    int r = idx >> 9;
    int b = r >> 4, s = r & 15;
    packed[idx] = tgt[((long)b * TCAP + s + 1) * DD + d];
}

// ---------------------------------------------------------------------------
extern "C" void kernel_launch(void* const* d_in, const int* in_sizes, int n_in,
                              void* d_out, int out_size, void* d_ws, size_t ws_size,
                              hipStream_t stream) {
    const float* x          = (const float*)d_in[0];
    const float* W_in       = (const float*)d_in[1];
    const float* b_in       = (const float*)d_in[2];
    const float* start_tok  = (const float*)d_in[3];
    const float* enc_qkv_w  = (const float*)d_in[4];
    const float* enc_qkv_b  = (const float*)d_in[5];
    const float* enc_out_w  = (const float*)d_in[6];
    const float* enc_out_b  = (const float*)d_in[7];
    const float* enc_ln1_g  = (const float*)d_in[8];
    const float* enc_ln1_b  = (const float*)d_in[9];
    const float* enc_ff1_w  = (const float*)d_in[10];
    const float* enc_ff1_b  = (const float*)d_in[11];
    const float* enc_ff2_w  = (const float*)d_in[12];
    const float* enc_ff2_b  = (const float*)d_in[13];
    const float* enc_ln2_g  = (const float*)d_in[14];
    const float* enc_ln2_b  = (const float*)d_in[15];
    const float* enc_norm_g = (const float*)d_in[16];
    const float* enc_norm_b = (const float*)d_in[17];
    const float* dsa_qkv_w  = (const float*)d_in[18];
    const float* dsa_qkv_b  = (const float*)d_in[19];
    const float* dsa_out_w  = (const float*)d_in[20];
    const float* dsa_out_b  = (const float*)d_in[21];
    const float* dln1_g     = (const float*)d_in[22];
    const float* dln1_b     = (const float*)d_in[23];
    const float* dca_qkv_w  = (const float*)d_in[24];
    const float* dca_qkv_b  = (const float*)d_in[25];
    const float* dca_out_w  = (const float*)d_in[26];
    const float* dca_out_b  = (const float*)d_in[27];
    const float* dln2_g     = (const float*)d_in[28];
    const float* dln2_b     = (const float*)d_in[29];
    const float* dff1_w     = (const float*)d_in[30];
    const float* dff1_b     = (const float*)d_in[31];
    const float* dff2_w     = (const float*)d_in[32];
    const float* dff2_b     = (const float*)d_in[33];
    const float* dln3_g     = (const float*)d_in[34];
    const float* dln3_b     = (const float*)d_in[35];
    const float* dnorm_g    = (const float*)d_in[36];
    const float* dnorm_b    = (const float*)d_in[37];
    const float* W_out      = (const float*)d_in[38];
    const float* b_out      = (const float*)d_in[39];
    // d_in[40] = description_length (fixed 16; hardcoded)

    float* ws = (float*)d_ws;
    const size_t A = AREG;
    // Five A-sized regions with tight lifetime reuse (peak 5A ≈ 168 MB):
    float* buf0 = ws;                 // src -> mem
    float* buf1 = ws + 1 * A;         // q   -> tmp -> tmp2
    float* buf2 = ws + 2 * A;         // k   -> h1  -> memK
    float* buf3 = ws + 3 * A;         // v   -> ff(lo)-> memV
    float* buf4 = ws + 4 * A;         // attn-> ff(hi)
    float* src  = buf0;
    float* qh   = buf1;               // q/k/v heads at buf1/buf2/buf3 (mode-2 scatter)
    float* attn = buf4;
    float* tmp  = buf1;
    float* h1   = buf2;
    float* ffbuf= buf3;               // [8192, 2048] chunk = 2A contiguous (buf3..buf4)
    float* tmp2 = buf1;
    float* mem  = buf0;
    float* memK = buf2;               // memV lands at buf3 via mode-2 which*A offset

    // decode-side small buffers at ws + 5A (~10.5 MB)
    float* sb     = ws + 5 * A;
    float* tgt    = sb;                      // BB*TCAP*DD = 557056
    float* kcache = tgt + BH17;              // 557056
    float* vcache = kcache + BH17;           // 557056 (contiguous with kcache)
    float* qbuf   = vcache + BH17;           // 32768 each below
    float* sao    = qbuf + 32768;
    float* tmpd   = sao + 32768;
    float* u      = tmpd + 32768;
    float* caq    = u + 32768;
    float* cao    = caq + 32768;
    float* tmpd2  = cao + 32768;
    float* u2     = tmpd2 + 32768;
    float* ffd    = u2 + 32768;              // 64*2048 = 131072
    float* tmpd3  = ffd + 131072;
    float* packed = tmpd3 + 32768;           // 64*16*512 = 524288

    auto gemm = [&](const float* Ap, int lda, const float* Wp, const float* bp,
                    float* outp, float* auxp, int M, int N, int K, int mode, int p1) {
        dim3 g((M + BM - 1) / BM, N / BN);
        gemm_k<<<g, 256, 0, stream>>>(Ap, lda, Wp, bp, outp, auxp, M, N, K, mode, p1);
    };
    auto ln = [&](const float* xp, long xs, const float* rp, long rs,
                  const float* g1, const float* b1, const float* g2, const float* b2,
                  float* op, long os, int nrows, int dbl) {
        ln_k<<<(nrows + 3) / 4, 256, 0, stream>>>(xp, xs, rp, rs, g1, b1, g2, b2, op, os, nrows, dbl);
    };

    const int MS = BB * SS;  // 16384

    // ---- Encoder ----
    gemm(x, DIN, W_in, b_in, src, nullptr, MS, DD, DIN, 0, 0);
    gemm(src, DD, enc_qkv_w, enc_qkv_b, qh, nullptr, MS, 3 * DD, DD, 2, 0);
    enc_attn_k<<<BB * NH, 256, 0, stream>>>(buf1, buf2, buf3, attn);
    gemm(attn, DD, enc_out_w, enc_out_b, tmp, nullptr, MS, DD, DD, 0, 0);
    ln(tmp, DD, src, DD, enc_ln1_g, enc_ln1_b, nullptr, nullptr, h1, DD, MS, 0);
    // FFN chunked over M/2 so ffbuf fits in 2A (buf3..buf4)
    for (int c = 0; c < 2; ++c) {
        int roff = c * (MS / 2);
        gemm(h1 + (long)roff * DD, DD, enc_ff1_w, enc_ff1_b, ffbuf, nullptr, MS / 2, DFF, DD, 1, 0);
        gemm(ffbuf, DFF, enc_ff2_w, enc_ff2_b, tmp2 + (long)roff * DD, nullptr, MS / 2, DD, DFF, 0, 0);
    }
    ln(tmp2, DD, h1, DD, enc_ln2_g, enc_ln2_b, enc_norm_g, enc_norm_b, mem, DD, MS, 1);
    // cross-attn K/V of mem (rows 512..1535 of dca_qkv_w are Wk,Wv)
    gemm(mem, DD, dca_qkv_w + 512 * 512, dca_qkv_b + 512, memK, nullptr, MS, 2 * DD, DD, 2, 0);

    // ---- Decoder (KV-cached, exact math) ----
    init_tgt_k<<<(BB * DD + 255) / 256, 256, 0, stream>>>(start_tok, tgt);

    for (int t = 0; t < TLEN; ++t) {
        gemm(tgt + t * DD, TCAP * DD, dsa_qkv_w, dsa_qkv_b, qbuf, kcache, BB, 3 * DD, DD, 4, t);
        dec_sa_k<<<BB * NH, 64, 0, stream>>>(qbuf, kcache, vcache, sao, t);
        gemm(sao, DD, dsa_out_w, dsa_out_b, tmpd, nullptr, BB, DD, DD, 0, 0);
        ln(tmpd, DD, tgt + t * DD, TCAP * DD, dln1_g, dln1_b, nullptr, nullptr, u, DD, BB, 0);
        gemm(u, DD, dca_qkv_w, dca_qkv_b, caq, nullptr, BB, DD, DD, 0, 0);
        dec_ca_k<<<BB * NH, 256, 0, stream>>>(caq, memK, memK + A, cao);
        gemm(cao, DD, dca_out_w, dca_out_b, tmpd2, nullptr, BB, DD, DD, 0, 0);
        ln(tmpd2, DD, u, DD, dln2_g, dln2_b, nullptr, nullptr, u2, DD, BB, 0);
        gemm(u2, DD, dff1_w, dff1_b, ffd, nullptr, BB, DFF, DD, 1, 0);
        gemm(ffd, DFF, dff2_w, dff2_b, tmpd3, nullptr, BB, DD, DFF, 0, 0);
        ln(tmpd3, DD, u2, DD, dln3_g, dln3_b, dnorm_g, dnorm_b, tgt + (t + 1) * DD, TCAP * DD, BB, 1);
    }

    // ---- Output projection ----
    pack_k<<<(BB * TLEN * DD + 255) / 256, 256, 0, stream>>>(tgt, packed);
    gemm(packed, DD, W_out, b_out, (float*)d_out, nullptr, BB * TLEN, DD, DD, 0, 0);
}

// Round 4
// 9163.527 us; speedup vs baseline: 1.3714x; 1.3714x over previous
//
#include <hip/hip_runtime.h>
#include <hip/hip_bf16.h>

// Problem constants (from setup_inputs)
#define BB   64      // batch
#define SS   256     // src sequence (16*16)
#define DD   512     // model dim
#define DFF  2048
#define DIN  256
#define NH   8
#define DH   64
#define TLEN 16      // description_length (fixed by setup)
#define TCAP 17      // tgt capacity (start token + 16)
#define DROWS 2      // batch rows per decode block

constexpr size_t AREG = (size_t)BB * SS * DD;   // 8,388,608 floats per [B,S,D] buffer
constexpr int    BH17 = BB * NH * TCAP * DH;    // 557,056

// ---------------------------------------------------------------------------
// Encoder fp32 GEMM: C[M,N] = A[M,K] @ W[N,K]^T + bias.
// mode 0: plain; mode 1: relu; mode 2: qkv head scatter
// 128x128x16 tile, 256 threads, 8x8 per-thread acc, register-prefetch dbuf.
// ---------------------------------------------------------------------------
#define BM 128
#define BN 128
#define BK 16

__global__ __launch_bounds__(256) void gemm_k(
    const float* __restrict__ A, int lda,
    const float* __restrict__ W,
    const float* __restrict__ bias,
    float* __restrict__ out,
    int M, int N, int K, int mode)
{
    __shared__ float sA[BK][BM + 4];
    __shared__ float sB[BK][BN + 4];

    const int row0 = blockIdx.x * BM;
    const int col0 = blockIdx.y * BN;
    const int tid  = threadIdx.x;
    const int tx   = tid & 15;        // N dir, 8 cols each
    const int ty   = tid >> 4;        // M dir, 8 rows each

    float acc[8][8];
    #pragma unroll
    for (int i = 0; i < 8; ++i)
        #pragma unroll
        for (int j = 0; j < 8; ++j) acc[i][j] = 0.f;

    const int ar  = tid >> 2;          // 0..63
    const int ac4 = (tid & 3) * 4;     // 0,4,8,12

    // register prefetch buffers (A tile: 2 float4, W tile: 2 float4)
    float4 pa[2], pb[2];
    auto load_tiles = [&](int k0) {
        #pragma unroll
        for (int i = 0; i < 2; ++i) {
            int grow = row0 + ar + i * 64;
            pa[i] = make_float4(0.f, 0.f, 0.f, 0.f);
            if (grow < M) pa[i] = *(const float4*)&A[(long)grow * lda + k0 + ac4];
            pb[i] = *(const float4*)&W[(long)(col0 + ar + i * 64) * K + k0 + ac4];
        }
    };

    load_tiles(0);
    for (int k0 = 0; k0 < K; k0 += BK) {
        // store prefetched regs to LDS (prev compute done per trailing barrier)
        #pragma unroll
        for (int i = 0; i < 2; ++i) {
            int r = ar + i * 64;
            sA[ac4 + 0][r] = pa[i].x; sA[ac4 + 1][r] = pa[i].y;
            sA[ac4 + 2][r] = pa[i].z; sA[ac4 + 3][r] = pa[i].w;
            sB[ac4 + 0][r] = pb[i].x; sB[ac4 + 1][r] = pb[i].y;
            sB[ac4 + 2][r] = pb[i].z; sB[ac4 + 3][r] = pb[i].w;
        }
        __syncthreads();

        // issue next tile's global loads; latency hides under compute below
        if (k0 + BK < K) load_tiles(k0 + BK);

        #pragma unroll
        for (int k = 0; k < BK; ++k) {
            float4 a0 = *(const float4*)&sA[k][ty * 8];
            float4 a1 = *(const float4*)&sA[k][ty * 8 + 4];
            float4 b0 = *(const float4*)&sB[k][tx * 8];
            float4 b1 = *(const float4*)&sB[k][tx * 8 + 4];
            float a[8] = {a0.x, a0.y, a0.z, a0.w, a1.x, a1.y, a1.z, a1.w};
            float b[8] = {b0.x, b0.y, b0.z, b0.w, b1.x, b1.y, b1.z, b1.w};
            #pragma unroll
            for (int i = 0; i < 8; ++i)
                #pragma unroll
                for (int j = 0; j < 8; ++j)
                    acc[i][j] = fmaf(a[i], b[j], acc[i][j]);
        }
        __syncthreads();
    }

    const int gcol0 = col0 + tx * 8;
    float4 bb0 = *(const float4*)&bias[gcol0];
    float4 bb1 = *(const float4*)&bias[gcol0 + 4];
    float bs[8] = {bb0.x, bb0.y, bb0.z, bb0.w, bb1.x, bb1.y, bb1.z, bb1.w};
    #pragma unroll
    for (int i = 0; i < 8; ++i) {
        int grow = row0 + ty * 8 + i;
        if (grow >= M) continue;
        float v[8];
        #pragma unroll
        for (int j = 0; j < 8; ++j) {
            v[j] = acc[i][j] + bs[j];
            if (mode == 1) v[j] = fmaxf(v[j], 0.f);
        }
        float4 v0 = make_float4(v[0], v[1], v[2], v[3]);
        float4 v1 = make_float4(v[4], v[5], v[6], v[7]);
        if (mode <= 1) {
            float* p = &out[(long)grow * N + gcol0];
            *(float4*)p = v0; *(float4*)(p + 4) = v1;
        } else { // mode 2
            int b = grow >> 8, s = grow & 255;
            int which = gcol0 >> 9;
            int h = (gcol0 >> 6) & 7, d = gcol0 & 63;
            float* p = &out[(long)which * AREG + (((b * 8 + h) * 256 + s) * 64 + d)];
            *(float4*)p = v0; *(float4*)(p + 4) = v1;
        }
    }
}

// ---------------------------------------------------------------------------
// Encoder fused attention: one block (256 thr) per (b,h); thread = 1 q row.
// ---------------------------------------------------------------------------
__global__ __launch_bounds__(256) void enc_attn_k(
    const float* __restrict__ q, const float* __restrict__ k,
    const float* __restrict__ v, float* __restrict__ out)
{
    const int bh = blockIdx.x;
    const int b = bh >> 3, h = bh & 7;
    const float* Q = q + (long)bh * SS * DH;
    const float* Kp = k + (long)bh * SS * DH;
    const float* Vp = v + (long)bh * SS * DH;
    const int t = threadIdx.x;

    __shared__ float4 sK[16][16];
    __shared__ float4 sV[16][16];

    float4 q4[16];
    #pragma unroll
    for (int i = 0; i < 16; ++i) q4[i] = *(const float4*)&Q[t * 64 + i * 4];

    float4 o4[16];
    #pragma unroll
    for (int i = 0; i < 16; ++i) o4[i] = make_float4(0.f, 0.f, 0.f, 0.f);
    float m = -1e30f, l = 0.f;

    const int r = t >> 4, c4 = t & 15;
    for (int c = 0; c < 16; ++c) {
        sK[r][c4] = *(const float4*)&Kp[(c * 16 + r) * 64 + c4 * 4];
        sV[r][c4] = *(const float4*)&Vp[(c * 16 + r) * 64 + c4 * 4];
        __syncthreads();

        float sc[16];
        #pragma unroll
        for (int kk = 0; kk < 16; ++kk) {
            float s = 0.f;
            #pragma unroll
            for (int i = 0; i < 16; ++i) {
                float4 kv = sK[kk][i];
                s = fmaf(q4[i].x, kv.x, s); s = fmaf(q4[i].y, kv.y, s);
                s = fmaf(q4[i].z, kv.z, s); s = fmaf(q4[i].w, kv.w, s);
            }
            sc[kk] = s * 0.125f;
        }
        float cm = sc[0];
        #pragma unroll
        for (int kk = 1; kk < 16; ++kk) cm = fmaxf(cm, sc[kk]);
        float mn = fmaxf(m, cm);
        float alpha = __expf(m - mn);
        float ps[16]; float psum = 0.f;
        #pragma unroll
        for (int kk = 0; kk < 16; ++kk) { ps[kk] = __expf(sc[kk] - mn); psum += ps[kk]; }
        l = l * alpha + psum;
        #pragma unroll
        for (int i = 0; i < 16; ++i) {
            o4[i].x *= alpha; o4[i].y *= alpha; o4[i].z *= alpha; o4[i].w *= alpha;
        }
        #pragma unroll
        for (int kk = 0; kk < 16; ++kk) {
            float p = ps[kk];
            #pragma unroll
            for (int i = 0; i < 16; ++i) {
                float4 vv = sV[kk][i];
                o4[i].x = fmaf(p, vv.x, o4[i].x); o4[i].y = fmaf(p, vv.y, o4[i].y);
                o4[i].z = fmaf(p, vv.z, o4[i].z); o4[i].w = fmaf(p, vv.w, o4[i].w);
            }
        }
        m = mn;
        __syncthreads();
    }

    float inv = 1.f / l;
    float* O = out + ((long)(b * SS + t)) * DD + h * DH;
    #pragma unroll
    for (int i = 0; i < 16; ++i) {
        float4 v_;
        v_.x = o4[i].x * inv; v_.y = o4[i].y * inv;
        v_.z = o4[i].z * inv; v_.w = o4[i].w * inv;
        *(float4*)&O[i * 4] = v_;
    }
}

// ---------------------------------------------------------------------------
// Encoder LayerNorm, wave per row. out = LN(x + r); dbl=1: LN2(LN1(x+r)).
// ---------------------------------------------------------------------------
__global__ __launch_bounds__(256) void ln_k(
    const float* __restrict__ x,
    const float* __restrict__ r,
    const float* __restrict__ g1, const float* __restrict__ b1,
    const float* __restrict__ g2, const float* __restrict__ b2,
    float* __restrict__ out, int nrows, int dbl)
{
    const int row = blockIdx.x * 4 + (threadIdx.x >> 6);
    if (row >= nrows) return;
    const int lane = threadIdx.x & 63;

    const float* X = x + (long)row * DD;
    const float* R = r + (long)row * DD;
    float y[8];
    {
        float4 a = *(const float4*)&X[lane * 4];
        float4 c = *(const float4*)&X[256 + lane * 4];
        float4 ra = *(const float4*)&R[lane * 4];
        float4 rc = *(const float4*)&R[256 + lane * 4];
        y[0] = a.x + ra.x; y[1] = a.y + ra.y; y[2] = a.z + ra.z; y[3] = a.w + ra.w;
        y[4] = c.x + rc.x; y[5] = c.y + rc.y; y[6] = c.z + rc.z; y[7] = c.w + rc.w;
    }
    float sum = 0.f, sq = 0.f;
    #pragma unroll
    for (int i = 0; i < 8; ++i) { sum += y[i]; sq = fmaf(y[i], y[i], sq); }
    #pragma unroll
    for (int off = 32; off; off >>= 1) {
        sum += __shfl_xor(sum, off);
        sq  += __shfl_xor(sq, off);
    }
    float mean = sum * (1.f / 512.f);
    float var  = sq * (1.f / 512.f) - mean * mean;
    float rstd = rsqrtf(var + 1e-5f);
    {
        float4 ga = *(const float4*)&g1[lane * 4];
        float4 gc = *(const float4*)&g1[256 + lane * 4];
        float4 ba = *(const float4*)&b1[lane * 4];
        float4 bc = *(const float4*)&b1[256 + lane * 4];
        float gs[8] = {ga.x, ga.y, ga.z, ga.w, gc.x, gc.y, gc.z, gc.w};
        float bs[8] = {ba.x, ba.y, ba.z, ba.w, bc.x, bc.y, bc.z, bc.w};
        #pragma unroll
        for (int i = 0; i < 8; ++i) y[i] = fmaf((y[i] - mean) * rstd, gs[i], bs[i]);
    }
    if (dbl) {
        float sum2 = 0.f, sq2 = 0.f;
        #pragma unroll
        for (int i = 0; i < 8; ++i) { sum2 += y[i]; sq2 = fmaf(y[i], y[i], sq2); }
        #pragma unroll
        for (int off = 32; off; off >>= 1) {
            sum2 += __shfl_xor(sum2, off);
            sq2  += __shfl_xor(sq2, off);
        }
        float mean2 = sum2 * (1.f / 512.f);
        float var2  = sq2 * (1.f / 512.f) - mean2 * mean2;
        float rstd2 = rsqrtf(var2 + 1e-5f);
        float4 ga = *(const float4*)&g2[lane * 4];
        float4 gc = *(const float4*)&g2[256 + lane * 4];
        float4 ba = *(const float4*)&b2[lane * 4];
        float4 bc = *(const float4*)&b2[256 + lane * 4];
        float gs[8] = {ga.x, ga.y, ga.z, ga.w, gc.x, gc.y, gc.z, gc.w};
        float bs[8] = {ba.x, ba.y, ba.z, ba.w, bc.x, bc.y, bc.z, bc.w};
        #pragma unroll
        for (int i = 0; i < 8; ++i) y[i] = fmaf((y[i] - mean2) * rstd2, gs[i], bs[i]);
    }
    float* O = out + (long)row * DD;
    *(float4*)&O[lane * 4] = make_float4(y[0], y[1], y[2], y[3]);
    *(float4*)&O[256 + lane * 4] = make_float4(y[4], y[5], y[6], y[7]);
}

// ===========================================================================
// DECODE KERNELS — block per DROWS batch rows, 512 threads, GEMV-style.
// ===========================================================================

// qkv projection of current token + KV-cache scatter.
__global__ __launch_bounds__(512) void dec_qkv_k(
    const float* __restrict__ tgt, const float* __restrict__ W,
    const float* __restrict__ bias, float* __restrict__ qbuf,
    float* __restrict__ kc, float* __restrict__ vc, int t)
{
    const int b0 = blockIdx.x * DROWS;
    const int j  = threadIdx.x;            // 0..511
    __shared__ float sx[DROWS][DD];
    #pragma unroll
    for (int r = 0; r < DROWS; ++r)
        sx[r][j] = tgt[((long)(b0 + r) * TCAP + t) * DD + j];
    __syncthreads();

    #pragma unroll
    for (int c = 0; c < 3; ++c) {
        const int col = c * DD + j;
        const float* Wr = W + (long)col * DD;
        float a0 = 0.f, a1 = 0.f;
        for (int k = 0; k < DD; k += 4) {
            float4 w4 = *(const float4*)&Wr[k];
            float4 x0 = *(const float4*)&sx[0][k];
            float4 x1 = *(const float4*)&sx[1][k];
            a0 = fmaf(x0.x, w4.x, a0); a0 = fmaf(x0.y, w4.y, a0);
            a0 = fmaf(x0.z, w4.z, a0); a0 = fmaf(x0.w, w4.w, a0);
            a1 = fmaf(x1.x, w4.x, a1); a1 = fmaf(x1.y, w4.y, a1);
            a1 = fmaf(x1.z, w4.z, a1); a1 = fmaf(x1.w, w4.w, a1);
        }
        float bv = bias[col];
        a0 += bv; a1 += bv;
        const int h = j >> 6, d = j & 63;
        if (c == 0) {
            qbuf[(b0 + 0) * DD + j] = a0;
            qbuf[(b0 + 1) * DD + j] = a1;
        } else {
            float* cache = (c == 1) ? kc : vc;
            cache[(((b0 + 0) * NH + h) * TCAP + t) * DH + d] = a0;
            cache[(((b0 + 1) * NH + h) * TCAP + t) * DH + d] = a1;
        }
    }
}

// Decode self-attention with KV cache. 1 wave per (b,h). L = t+1 keys.
__global__ __launch_bounds__(64) void dec_sa_k(
    const float* __restrict__ qbuf, const float* __restrict__ kc,
    const float* __restrict__ vc, float* __restrict__ out, int t)
{
    const int bh = blockIdx.x;
    const int b = bh >> 3, h = bh & 7;
    const int lane = threadIdx.x;
    const int L = t + 1;

    __shared__ float sq[64];
    __shared__ float sp[64];

    sq[lane] = qbuf[b * DD + h * DH + lane];
    __syncthreads();

    const float* K = kc + (long)bh * TCAP * DH;
    float s = -1e30f;
    if (lane < L) {
        float acc = 0.f;
        #pragma unroll
        for (int d = 0; d < 64; d += 4) {
            float4 kr = *(const float4*)&K[lane * 64 + d];
            acc = fmaf(sq[d], kr.x, acc); acc = fmaf(sq[d + 1], kr.y, acc);
            acc = fmaf(sq[d + 2], kr.z, acc); acc = fmaf(sq[d + 3], kr.w, acc);
        }
        s = acc * 0.125f;
    }
    float mx = s;
    #pragma unroll
    for (int off = 32; off; off >>= 1) mx = fmaxf(mx, __shfl_xor(mx, off));
    float p = (lane < L) ? __expf(s - mx) : 0.f;
    float sum = p;
    #pragma unroll
    for (int off = 32; off; off >>= 1) sum += __shfl_xor(sum, off);
    sp[lane] = p;
    __syncthreads();

    const float* V = vc + (long)bh * TCAP * DH;
    float o = 0.f;
    for (int kk = 0; kk < L; ++kk) o = fmaf(sp[kk], V[kk * 64 + lane], o);
    out[b * DD + h * DH + lane] = o / sum;
}

// sa out-proj + residual + LN -> u ; then caq = u @ Wq^T + bq (fused).
__global__ __launch_bounds__(512) void dec_saproj_k(
    const float* __restrict__ sao, const float* __restrict__ Wo,
    const float* __restrict__ bo, const float* __restrict__ tgt, int t,
    const float* __restrict__ g1, const float* __restrict__ b1,
    const float* __restrict__ Wq, const float* __restrict__ bq,
    float* __restrict__ u, float* __restrict__ caq)
{
    const int b0 = blockIdx.x * DROWS;
    const int j = threadIdx.x;
    const int w = j >> 6, lane = j & 63;
    __shared__ float sx[DROWS][DD];
    __shared__ float su[DROWS][DD];
    __shared__ float red[DROWS][16];

    #pragma unroll
    for (int r = 0; r < DROWS; ++r) sx[r][j] = sao[(b0 + r) * DD + j];
    __syncthreads();

    float acc[DROWS] = {0.f, 0.f};
    {
        const float* Wr = Wo + (long)j * DD;
        for (int k = 0; k < DD; k += 4) {
            float4 w4 = *(const float4*)&Wr[k];
            float4 x0 = *(const float4*)&sx[0][k];
            float4 x1 = *(const float4*)&sx[1][k];
            acc[0] = fmaf(x0.x, w4.x, acc[0]); acc[0] = fmaf(x0.y, w4.y, acc[0]);
            acc[0] = fmaf(x0.z, w4.z, acc[0]); acc[0] = fmaf(x0.w, w4.w, acc[0]);
            acc[1] = fmaf(x1.x, w4.x, acc[1]); acc[1] = fmaf(x1.y, w4.y, acc[1]);
            acc[1] = fmaf(x1.z, w4.z, acc[1]); acc[1] = fmaf(x1.w, w4.w, acc[1]);
        }
    }
    #pragma unroll
    for (int r = 0; r < DROWS; ++r)
        acc[r] += bo[j] + tgt[((long)(b0 + r) * TCAP + t) * DD + j];

    #pragma unroll
    for (int r = 0; r < DROWS; ++r) {
        float s1 = acc[r], s2 = acc[r] * acc[r];
        #pragma unroll
        for (int off = 32; off; off >>= 1) {
            s1 += __shfl_xor(s1, off); s2 += __shfl_xor(s2, off);
        }
        if (lane == 0) { red[r][w] = s1; red[r][8 + w] = s2; }
    }
    __syncthreads();
    #pragma unroll
    for (int r = 0; r < DROWS; ++r) {
        float sum = 0.f, sq = 0.f;
        #pragma unroll
        for (int i = 0; i < 8; ++i) { sum += red[r][i]; sq += red[r][8 + i]; }
        float mean = sum * (1.f / 512.f);
        float var  = sq * (1.f / 512.f) - mean * mean;
        float rstd = rsqrtf(var + 1e-5f);
        float uv = fmaf((acc[r] - mean) * rstd, g1[j], b1[j]);
        su[r][j] = uv;
        u[(b0 + r) * DD + j] = uv;
    }
    __syncthreads();

    float q0 = 0.f, q1 = 0.f;
    {
        const float* Wr = Wq + (long)j * DD;
        for (int k = 0; k < DD; k += 4) {
            float4 w4 = *(const float4*)&Wr[k];
            float4 x0 = *(const float4*)&su[0][k];
            float4 x1 = *(const float4*)&su[1][k];
            q0 = fmaf(x0.x, w4.x, q0); q0 = fmaf(x0.y, w4.y, q0);
            q0 = fmaf(x0.z, w4.z, q0); q0 = fmaf(x0.w, w4.w, q0);
            q1 = fmaf(x1.x, w4.x, q1); q1 = fmaf(x1.y, w4.y, q1);
            q1 = fmaf(x1.z, w4.z, q1); q1 = fmaf(x1.w, w4.w, q1);
        }
    }
    float bv = bq[j];
    caq[(b0 + 0) * DD + j] = q0 + bv;
    caq[(b0 + 1) * DD + j] = q1 + bv;
}

// Decode cross-attention over mem (256 keys). 256 threads per (b,h).
__global__ __launch_bounds__(256) void dec_ca_k(
    const float* __restrict__ caq, const float* __restrict__ mk,
    const float* __restrict__ mv, float* __restrict__ out)
{
    const int bh = blockIdx.x;
    const int b = bh >> 3, h = bh & 7;
    const int tid = threadIdx.x;

    __shared__ float sq[64];
    __shared__ float sp[256];
    __shared__ float red[8];
    __shared__ float so[4][64];

    if (tid < 64) sq[tid] = caq[b * DD + h * DH + tid];
    __syncthreads();

    const float* K = mk + (long)bh * SS * DH;
    float acc = 0.f;
    #pragma unroll
    for (int d = 0; d < 64; d += 4) {
        float4 kr = *(const float4*)&K[tid * 64 + d];
        acc = fmaf(sq[d], kr.x, acc); acc = fmaf(sq[d + 1], kr.y, acc);
        acc = fmaf(sq[d + 2], kr.z, acc); acc = fmaf(sq[d + 3], kr.w, acc);
    }
    float s = acc * 0.125f;

    float mx = s;
    #pragma unroll
    for (int off = 32; off; off >>= 1) mx = fmaxf(mx, __shfl_xor(mx, off));
    const int w = tid >> 6;
    if ((tid & 63) == 0) red[w] = mx;
    __syncthreads();
    mx = fmaxf(fmaxf(red[0], red[1]), fmaxf(red[2], red[3]));

    float p = __expf(s - mx);
    sp[tid] = p;
    float sum = p;
    #pragma unroll
    for (int off = 32; off; off >>= 1) sum += __shfl_xor(sum, off);
    if ((tid & 63) == 0) red[4 + w] = sum;
    __syncthreads();
    sum = red[4] + red[5] + red[6] + red[7];

    const float* V = mv + (long)bh * SS * DH;
    const int d = tid & 63;
    float o = 0.f;
    for (int kk = 0; kk < 64; ++kk) {
        int krow = w * 64 + kk;
        o = fmaf(sp[krow], V[krow * 64 + d], o);
    }
    so[w][d] = o;
    __syncthreads();
    if (tid < 64) {
        float rslt = (so[0][tid] + so[1][tid] + so[2][tid] + so[3][tid]) / sum;
        out[b * DD + h * DH + tid] = rslt;
    }
}

// ca out-proj + residual(u) + LN -> u2 ; FF1+relu ; FF2 + residual(u2)
// + LN + final LN -> tgt[:, t+1, :]. All fused, block per DROWS rows.
__global__ __launch_bounds__(512) void dec_tail_k(
    const float* __restrict__ cao, const float* __restrict__ Wo,
    const float* __restrict__ bo, const float* __restrict__ u,
    const float* __restrict__ g2, const float* __restrict__ b2,
    const float* __restrict__ W1, const float* __restrict__ bb1,
    const float* __restrict__ W2, const float* __restrict__ bb2,
    const float* __restrict__ g3, const float* __restrict__ b3,
    const float* __restrict__ gn, const float* __restrict__ bn,
    float* __restrict__ tgt, int t)
{
    const int b0 = blockIdx.x * DROWS;
    const int j = threadIdx.x;
    const int w = j >> 6, lane = j & 63;
    __shared__ float sx[DROWS][DD];
    __shared__ float su2[DROWS][DD];
    __shared__ float sf[DROWS][DFF];
    __shared__ float red[DROWS][16];

    #pragma unroll
    for (int r = 0; r < DROWS; ++r) sx[r][j] = cao[(b0 + r) * DD + j];
    __syncthreads();

    // ca out-proj + residual u
    float acc[DROWS] = {0.f, 0.f};
    {
        const float* Wr = Wo + (long)j * DD;
        for (int k = 0; k < DD; k += 4) {
            float4 w4 = *(const float4*)&Wr[k];
            float4 x0 = *(const float4*)&sx[0][k];
            float4 x1 = *(const float4*)&sx[1][k];
            acc[0] = fmaf(x0.x, w4.x, acc[0]); acc[0] = fmaf(x0.y, w4.y, acc[0]);
            acc[0] = fmaf(x0.z, w4.z, acc[0]); acc[0] = fmaf(x0.w, w4.w, acc[0]);
            acc[1] = fmaf(x1.x, w4.x, acc[1]); acc[1] = fmaf(x1.y, w4.y, acc[1]);
            acc[1] = fmaf(x1.z, w4.z, acc[1]); acc[1] = fmaf(x1.w, w4.w, acc[1]);
        }
    }
    #pragma unroll
    for (int r = 0; r < DROWS; ++r)
        acc[r] += bo[j] + u[(b0 + r) * DD + j];

    // LN(g2,b2) -> su2
    #pragma unroll
    for (int r = 0; r < DROWS; ++r) {
        float s1 = acc[r], s2 = acc[r] * acc[r];
        #pragma unroll
        for (int off = 32; off; off >>= 1) {
            s1 += __shfl_xor(s1, off); s2 += __shfl_xor(s2, off);
        }
        if (lane == 0) { red[r][w] = s1; red[r][8 + w] = s2; }
    }
    __syncthreads();
    #pragma unroll
    for (int r = 0; r < DROWS; ++r) {
        float sum = 0.f, sq = 0.f;
        #pragma unroll
        for (int i = 0; i < 8; ++i) { sum += red[r][i]; sq += red[r][8 + i]; }
        float mean = sum * (1.f / 512.f);
        float var  = sq * (1.f / 512.f) - mean * mean;
        float rstd = rsqrtf(var + 1e-5f);
        su2[r][j] = fmaf((acc[r] - mean) * rstd, g2[j], b2[j]);
    }
    __syncthreads();

    // FF1 + relu -> sf (4 cols per thread)
    #pragma unroll
    for (int c = 0; c < 4; ++c) {
        const int col = c * DD + j;
        const float* Wr = W1 + (long)col * DD;
        float f0 = 0.f, f1 = 0.f;
        for (int k = 0; k < DD; k += 4) {
            float4 w4 = *(const float4*)&Wr[k];
            float4 x0 = *(const float4*)&su2[0][k];
            float4 x1 = *(const float4*)&su2[1][k];
            f0 = fmaf(x0.x, w4.x, f0); f0 = fmaf(x0.y, w4.y, f0);
            f0 = fmaf(x0.z, w4.z, f0); f0 = fmaf(x0.w, w4.w, f0);
            f1 = fmaf(x1.x, w4.x, f1); f1 = fmaf(x1.y, w4.y, f1);
            f1 = fmaf(x1.z, w4.z, f1); f1 = fmaf(x1.w, w4.w, f1);
        }
        float bv = bb1[col];
        sf[0][col] = fmaxf(f0 + bv, 0.f);
        sf[1][col] = fmaxf(f1 + bv, 0.f);
    }
    __syncthreads();

    // FF2 + residual su2
    float a2[DROWS] = {0.f, 0.f};
    {
        const float* Wr = W2 + (long)j * DFF;
        for (int k = 0; k < DFF; k += 4) {
            float4 w4 = *(const float4*)&Wr[k];
            float4 x0 = *(const float4*)&sf[0][k];
            float4 x1 = *(const float4*)&sf[1][k];
            a2[0] = fmaf(x0.x, w4.x, a2[0]); a2[0] = fmaf(x0.y, w4.y, a2[0]);
            a2[0] = fmaf(x0.z, w4.z, a2[0]); a2[0] = fmaf(x0.w, w4.w, a2[0]);
            a2[1] = fmaf(x1.x, w4.x, a2[1]); a2[1] = fmaf(x1.y, w4.y, a2[1]);
            a2[1] = fmaf(x1.z, w4.z, a2[1]); a2[1] = fmaf(x1.w, w4.w, a2[1]);
        }
    }
    #pragma unroll
    for (int r = 0; r < DROWS; ++r)
        a2[r] += bb2[j] + su2[r][j];

    // LN(g3,b3)
    float y[DROWS];
    __syncthreads();   // red safe to reuse
    #pragma unroll
    for (int r = 0; r < DROWS; ++r) {
        float s1 = a2[r], s2 = a2[r] * a2[r];
        #pragma unroll
        for (int off = 32; off; off >>= 1) {
            s1 += __shfl_xor(s1, off); s2 += __shfl_xor(s2, off);
        }
        if (lane == 0) { red[r][w] = s1; red[r][8 + w] = s2; }
    }
    __syncthreads();
    #pragma unroll
    for (int r = 0; r < DROWS; ++r) {
        float sum = 0.f, sq = 0.f;
        #pragma unroll
        for (int i = 0; i < 8; ++i) { sum += red[r][i]; sq += red[r][8 + i]; }
        float mean = sum * (1.f / 512.f);
        float var  = sq * (1.f / 512.f) - mean * mean;
        float rstd = rsqrtf(var + 1e-5f);
        y[r] = fmaf((a2[r] - mean) * rstd, g3[j], b3[j]);
    }
    // final LN(gn,bn)
    __syncthreads();
    #pragma unroll
    for (int r = 0; r < DROWS; ++r) {
        float s1 = y[r], s2 = y[r] * y[r];
        #pragma unroll
        for (int off = 32; off; off >>= 1) {
            s1 += __shfl_xor(s1, off); s2 += __shfl_xor(s2, off);
        }
        if (lane == 0) { red[r][w] = s1; red[r][8 + w] = s2; }
    }
    __syncthreads();
    #pragma unroll
    for (int r = 0; r < DROWS; ++r) {
        float sum = 0.f, sq = 0.f;
        #pragma unroll
        for (int i = 0; i < 8; ++i) { sum += red[r][i]; sq += red[r][8 + i]; }
        float mean = sum * (1.f / 512.f);
        float var  = sq * (1.f / 512.f) - mean * mean;
        float rstd = rsqrtf(var + 1e-5f);
        float out = fmaf((y[r] - mean) * rstd, gn[j], bn[j]);
        tgt[((long)(b0 + r) * TCAP + t + 1) * DD + j] = out;
    }
}

// tgt[:,0,:] = start_token
__global__ __launch_bounds__(256) void init_tgt_k(
    const float* __restrict__ start, float* __restrict__ tgt)
{
    int idx = blockIdx.x * 256 + threadIdx.x;
    if (idx >= BB * DD) return;
    int b = idx >> 9, d = idx & 511;
    tgt[(long)b * TCAP * DD + d] = start[d];
}

// packed[b*16+s][d] = tgt[b][s+1][d]
__global__ __launch_bounds__(256) void pack_k(
    const float* __restrict__ tgt, float* __restrict__ packed)
{
    int idx = blockIdx.x * 256 + threadIdx.x;
    if (idx >= BB * TLEN * DD) return;
    int d = idx & 511;
    int r = idx >> 9;
    int b = r >> 4, s = r & 15;
    packed[idx] = tgt[((long)b * TCAP + s + 1) * DD + d];
}

// ---------------------------------------------------------------------------
extern "C" void kernel_launch(void* const* d_in, const int* in_sizes, int n_in,
                              void* d_out, int out_size, void* d_ws, size_t ws_size,
                              hipStream_t stream) {
    const float* x          = (const float*)d_in[0];
    const float* W_in       = (const float*)d_in[1];
    const float* b_in       = (const float*)d_in[2];
    const float* start_tok  = (const float*)d_in[3];
    const float* enc_qkv_w  = (const float*)d_in[4];
    const float* enc_qkv_b  = (const float*)d_in[5];
    const float* enc_out_w  = (const float*)d_in[6];
    const float* enc_out_b  = (const float*)d_in[7];
    const float* enc_ln1_g  = (const float*)d_in[8];
    const float* enc_ln1_b  = (const float*)d_in[9];
    const float* enc_ff1_w  = (const float*)d_in[10];
    const float* enc_ff1_b  = (const float*)d_in[11];
    const float* enc_ff2_w  = (const float*)d_in[12];
    const float* enc_ff2_b  = (const float*)d_in[13];
    const float* enc_ln2_g  = (const float*)d_in[14];
    const float* enc_ln2_b  = (const float*)d_in[15];
    const float* enc_norm_g = (const float*)d_in[16];
    const float* enc_norm_b = (const float*)d_in[17];
    const float* dsa_qkv_w  = (const float*)d_in[18];
    const float* dsa_qkv_b  = (const float*)d_in[19];
    const float* dsa_out_w  = (const float*)d_in[20];
    const float* dsa_out_b  = (const float*)d_in[21];
    const float* dln1_g     = (const float*)d_in[22];
    const float* dln1_b     = (const float*)d_in[23];
    const float* dca_qkv_w  = (const float*)d_in[24];
    const float* dca_qkv_b  = (const float*)d_in[25];
    const float* dca_out_w  = (const float*)d_in[26];
    const float* dca_out_b  = (const float*)d_in[27];
    const float* dln2_g     = (const float*)d_in[28];
    const float* dln2_b     = (const float*)d_in[29];
    const float* dff1_w     = (const float*)d_in[30];
    const float* dff1_b     = (const float*)d_in[31];
    const float* dff2_w     = (const float*)d_in[32];
    const float* dff2_b     = (const float*)d_in[33];
    const float* dln3_g     = (const float*)d_in[34];
    const float* dln3_b     = (const float*)d_in[35];
    const float* dnorm_g    = (const float*)d_in[36];
    const float* dnorm_b    = (const float*)d_in[37];
    const float* W_out      = (const float*)d_in[38];
    const float* b_out      = (const float*)d_in[39];
    // d_in[40] = description_length (fixed 16; hardcoded)

    float* ws = (float*)d_ws;
    const size_t A = AREG;
    float* buf0 = ws;                 // src -> mem
    float* buf1 = ws + 1 * A;         // q   -> tmp -> tmp2
    float* buf2 = ws + 2 * A;         // k   -> h1  -> memK
    float* buf3 = ws + 3 * A;         // v   -> ff(lo)-> memV
    float* buf4 = ws + 4 * A;         // attn-> ff(hi)
    float* src  = buf0;
    float* qh   = buf1;
    float* attn = buf4;
    float* tmp  = buf1;
    float* h1   = buf2;
    float* ffbuf= buf3;               // [8192, 2048] = 2A (buf3..buf4)
    float* tmp2 = buf1;
    float* mem  = buf0;
    float* memK = buf2;               // memV at buf3 (mode-2 which*A)

    float* sb     = ws + 5 * A;
    float* tgt    = sb;                      // BB*TCAP*DD = 557056
    float* kcache = tgt + BH17;              // 557056
    float* vcache = kcache + BH17;           // 557056
    float* qbuf   = vcache + BH17;
    float* sao    = qbuf + 32768;
    float* u      = sao + 32768;
    float* caq    = u + 32768;
    float* cao    = caq + 32768;
    float* packed = cao + 32768;             // 524288

    auto gemm = [&](const float* Ap, int lda, const float* Wp, const float* bp,
                    float* outp, int M, int N, int K, int mode) {
        dim3 g((M + BM - 1) / BM, N / BN);
        gemm_k<<<g, 256, 0, stream>>>(Ap, lda, Wp, bp, outp, M, N, K, mode);
    };
    auto ln = [&](const float* xp, const float* rp,
                  const float* g1, const float* b1, const float* g2, const float* b2,
                  float* op, int nrows, int dbl) {
        ln_k<<<(nrows + 3) / 4, 256, 0, stream>>>(xp, rp, g1, b1, g2, b2, op, nrows, dbl);
    };

    const int MS = BB * SS;  // 16384

    // ---- Encoder ----
    gemm(x, DIN, W_in, b_in, src, MS, DD, DIN, 0);
    gemm(src, DD, enc_qkv_w, enc_qkv_b, qh, MS, 3 * DD, DD, 2);
    enc_attn_k<<<BB * NH, 256, 0, stream>>>(buf1, buf2, buf3, attn);
    gemm(attn, DD, enc_out_w, enc_out_b, tmp, MS, DD, DD, 0);
    ln(tmp, src, enc_ln1_g, enc_ln1_b, nullptr, nullptr, h1, MS, 0);
    for (int c = 0; c < 2; ++c) {
        int roff = c * (MS / 2);
        gemm(h1 + (long)roff * DD, DD, enc_ff1_w, enc_ff1_b, ffbuf, MS / 2, DFF, DD, 1);
        gemm(ffbuf, DFF, enc_ff2_w, enc_ff2_b, tmp2 + (long)roff * DD, MS / 2, DD, DFF, 0);
    }
    ln(tmp2, h1, enc_ln2_g, enc_ln2_b, enc_norm_g, enc_norm_b, mem, MS, 1);
    gemm(mem, DD, dca_qkv_w + 512 * 512, dca_qkv_b + 512, memK, MS, 2 * DD, DD, 2);

    // ---- Decoder (KV-cached, fused row-block kernels) ----
    init_tgt_k<<<(BB * DD + 255) / 256, 256, 0, stream>>>(start_tok, tgt);

    const int DG = BB / DROWS;  // 32 blocks
    for (int t = 0; t < TLEN; ++t) {
        dec_qkv_k<<<DG, 512, 0, stream>>>(tgt, dsa_qkv_w, dsa_qkv_b, qbuf, kcache, vcache, t);
        dec_sa_k<<<BB * NH, 64, 0, stream>>>(qbuf, kcache, vcache, sao, t);
        dec_saproj_k<<<DG, 512, 0, stream>>>(sao, dsa_out_w, dsa_out_b, tgt, t,
                                             dln1_g, dln1_b, dca_qkv_w, dca_qkv_b, u, caq);
        dec_ca_k<<<BB * NH, 256, 0, stream>>>(caq, memK, memK + A, cao);
        dec_tail_k<<<DG, 512, 0, stream>>>(cao, dca_out_w, dca_out_b, u,
                                           dln2_g, dln2_b, dff1_w, dff1_b,
                                           dff2_w, dff2_b, dln3_g, dln3_b,
                                           dnorm_g, dnorm_b, tgt, t);
    }

    // ---- Output projection ----
    pack_k<<<(BB * TLEN * DD + 255) / 256, 256, 0, stream>>>(tgt, packed);
    gemm(packed, DD, W_out, b_out, (float*)d_out, BB * TLEN, DD, DD, 0);
}

// Round 5
// 8387.244 us; speedup vs baseline: 1.4983x; 1.0926x over previous
//
#include <hip/hip_runtime.h>
#include <hip/hip_bf16.h>

// Problem constants (from setup_inputs)
#define BB   64      // batch
#define SS   256     // src sequence (16*16)
#define DD   512     // model dim
#define DFF  2048
#define DIN  256
#define NH   8
#define DH   64
#define TLEN 16      // description_length (fixed by setup)
#define TCAP 17      // tgt capacity (start token + 16)
#define DROWS 2      // batch rows per decode block

constexpr size_t AREG = (size_t)BB * SS * DD;   // 8,388,608 floats per [B,S,D] buffer
constexpr int    BH17 = BB * NH * TCAP * DH;    // 557,056

// ---------------------------------------------------------------------------
// Encoder fp32 GEMM: C[M,N] = A[M,K] @ W[N,K]^T + bias.
// mode 0: plain; mode 1: relu; mode 2: qkv head scatter
// 128x128x16 tile, 256 threads, 8x8 per-thread acc, register-prefetch dbuf.
// ---------------------------------------------------------------------------
#define BM 128
#define BN 128
#define BK 16

__global__ __launch_bounds__(256) void gemm_k(
    const float* __restrict__ A, int lda,
    const float* __restrict__ W,
    const float* __restrict__ bias,
    float* __restrict__ out,
    int M, int N, int K, int mode)
{
    __shared__ float sA[BK][BM + 4];
    __shared__ float sB[BK][BN + 4];

    const int row0 = blockIdx.x * BM;
    const int col0 = blockIdx.y * BN;
    const int tid  = threadIdx.x;
    const int tx   = tid & 15;        // N dir, 8 cols each
    const int ty   = tid >> 4;        // M dir, 8 rows each

    float acc[8][8];
    #pragma unroll
    for (int i = 0; i < 8; ++i)
        #pragma unroll
        for (int j = 0; j < 8; ++j) acc[i][j] = 0.f;

    const int ar  = tid >> 2;          // 0..63
    const int ac4 = (tid & 3) * 4;     // 0,4,8,12

    float4 pa[2], pb[2];
    auto load_tiles = [&](int k0) {
        #pragma unroll
        for (int i = 0; i < 2; ++i) {
            int grow = row0 + ar + i * 64;
            pa[i] = make_float4(0.f, 0.f, 0.f, 0.f);
            if (grow < M) pa[i] = *(const float4*)&A[(long)grow * lda + k0 + ac4];
            pb[i] = *(const float4*)&W[(long)(col0 + ar + i * 64) * K + k0 + ac4];
        }
    };

    load_tiles(0);
    for (int k0 = 0; k0 < K; k0 += BK) {
        #pragma unroll
        for (int i = 0; i < 2; ++i) {
            int r = ar + i * 64;
            sA[ac4 + 0][r] = pa[i].x; sA[ac4 + 1][r] = pa[i].y;
            sA[ac4 + 2][r] = pa[i].z; sA[ac4 + 3][r] = pa[i].w;
            sB[ac4 + 0][r] = pb[i].x; sB[ac4 + 1][r] = pb[i].y;
            sB[ac4 + 2][r] = pb[i].z; sB[ac4 + 3][r] = pb[i].w;
        }
        __syncthreads();

        if (k0 + BK < K) load_tiles(k0 + BK);

        #pragma unroll
        for (int k = 0; k < BK; ++k) {
            float4 a0 = *(const float4*)&sA[k][ty * 8];
            float4 a1 = *(const float4*)&sA[k][ty * 8 + 4];
            float4 b0 = *(const float4*)&sB[k][tx * 8];
            float4 b1 = *(const float4*)&sB[k][tx * 8 + 4];
            float a[8] = {a0.x, a0.y, a0.z, a0.w, a1.x, a1.y, a1.z, a1.w};
            float b[8] = {b0.x, b0.y, b0.z, b0.w, b1.x, b1.y, b1.z, b1.w};
            #pragma unroll
            for (int i = 0; i < 8; ++i)
                #pragma unroll
                for (int j = 0; j < 8; ++j)
                    acc[i][j] = fmaf(a[i], b[j], acc[i][j]);
        }
        __syncthreads();
    }

    const int gcol0 = col0 + tx * 8;
    float4 bb0 = *(const float4*)&bias[gcol0];
    float4 bb1 = *(const float4*)&bias[gcol0 + 4];
    float bs[8] = {bb0.x, bb0.y, bb0.z, bb0.w, bb1.x, bb1.y, bb1.z, bb1.w};
    #pragma unroll
    for (int i = 0; i < 8; ++i) {
        int grow = row0 + ty * 8 + i;
        if (grow >= M) continue;
        float v[8];
        #pragma unroll
        for (int j = 0; j < 8; ++j) {
            v[j] = acc[i][j] + bs[j];
            if (mode == 1) v[j] = fmaxf(v[j], 0.f);
        }
        float4 v0 = make_float4(v[0], v[1], v[2], v[3]);
        float4 v1 = make_float4(v[4], v[5], v[6], v[7]);
        if (mode <= 1) {
            float* p = &out[(long)grow * N + gcol0];
            *(float4*)p = v0; *(float4*)(p + 4) = v1;
        } else { // mode 2
            int b = grow >> 8, s = grow & 255;
            int which = gcol0 >> 9;
            int h = (gcol0 >> 6) & 7, d = gcol0 & 63;
            float* p = &out[(long)which * AREG + (((b * 8 + h) * 256 + s) * 64 + d)];
            *(float4*)p = v0; *(float4*)(p + 4) = v1;
        }
    }
}

// ---------------------------------------------------------------------------
// Tiled transpose: WT[k][n] = W[n][k]. N, K multiples of 32.
// ---------------------------------------------------------------------------
__global__ __launch_bounds__(256) void tr_k(
    const float* __restrict__ W, float* __restrict__ WT, int N, int K)
{
    __shared__ float tile[32][33];
    const int n0 = blockIdx.x * 32, k0 = blockIdx.y * 32;
    const int tx = threadIdx.x & 31, ty = threadIdx.x >> 5;  // 32 x 8
    #pragma unroll
    for (int i = 0; i < 4; ++i)
        tile[ty + i * 8][tx] = W[(long)(n0 + ty + i * 8) * K + k0 + tx];
    __syncthreads();
    #pragma unroll
    for (int i = 0; i < 4; ++i)
        WT[(long)(k0 + ty + i * 8) * N + n0 + tx] = tile[tx][ty + i * 8];
}

// ---------------------------------------------------------------------------
// Encoder fused attention: one block (256 thr) per (b,h); thread = 1 q row.
// ---------------------------------------------------------------------------
__global__ __launch_bounds__(256) void enc_attn_k(
    const float* __restrict__ q, const float* __restrict__ k,
    const float* __restrict__ v, float* __restrict__ out)
{
    const int bh = blockIdx.x;
    const int b = bh >> 3, h = bh & 7;
    const float* Q = q + (long)bh * SS * DH;
    const float* Kp = k + (long)bh * SS * DH;
    const float* Vp = v + (long)bh * SS * DH;
    const int t = threadIdx.x;

    __shared__ float4 sK[16][16];
    __shared__ float4 sV[16][16];

    float4 q4[16];
    #pragma unroll
    for (int i = 0; i < 16; ++i) q4[i] = *(const float4*)&Q[t * 64 + i * 4];

    float4 o4[16];
    #pragma unroll
    for (int i = 0; i < 16; ++i) o4[i] = make_float4(0.f, 0.f, 0.f, 0.f);
    float m = -1e30f, l = 0.f;

    const int r = t >> 4, c4 = t & 15;
    for (int c = 0; c < 16; ++c) {
        sK[r][c4] = *(const float4*)&Kp[(c * 16 + r) * 64 + c4 * 4];
        sV[r][c4] = *(const float4*)&Vp[(c * 16 + r) * 64 + c4 * 4];
        __syncthreads();

        float sc[16];
        #pragma unroll
        for (int kk = 0; kk < 16; ++kk) {
            float s = 0.f;
            #pragma unroll
            for (int i = 0; i < 16; ++i) {
                float4 kv = sK[kk][i];
                s = fmaf(q4[i].x, kv.x, s); s = fmaf(q4[i].y, kv.y, s);
                s = fmaf(q4[i].z, kv.z, s); s = fmaf(q4[i].w, kv.w, s);
            }
            sc[kk] = s * 0.125f;
        }
        float cm = sc[0];
        #pragma unroll
        for (int kk = 1; kk < 16; ++kk) cm = fmaxf(cm, sc[kk]);
        float mn = fmaxf(m, cm);
        float alpha = __expf(m - mn);
        float ps[16]; float psum = 0.f;
        #pragma unroll
        for (int kk = 0; kk < 16; ++kk) { ps[kk] = __expf(sc[kk] - mn); psum += ps[kk]; }
        l = l * alpha + psum;
        #pragma unroll
        for (int i = 0; i < 16; ++i) {
            o4[i].x *= alpha; o4[i].y *= alpha; o4[i].z *= alpha; o4[i].w *= alpha;
        }
        #pragma unroll
        for (int kk = 0; kk < 16; ++kk) {
            float p = ps[kk];
            #pragma unroll
            for (int i = 0; i < 16; ++i) {
                float4 vv = sV[kk][i];
                o4[i].x = fmaf(p, vv.x, o4[i].x); o4[i].y = fmaf(p, vv.y, o4[i].y);
                o4[i].z = fmaf(p, vv.z, o4[i].z); o4[i].w = fmaf(p, vv.w, o4[i].w);
            }
        }
        m = mn;
        __syncthreads();
    }

    float inv = 1.f / l;
    float* O = out + ((long)(b * SS + t)) * DD + h * DH;
    #pragma unroll
    for (int i = 0; i < 16; ++i) {
        float4 v_;
        v_.x = o4[i].x * inv; v_.y = o4[i].y * inv;
        v_.z = o4[i].z * inv; v_.w = o4[i].w * inv;
        *(float4*)&O[i * 4] = v_;
    }
}

// ---------------------------------------------------------------------------
// Encoder LayerNorm, wave per row. out = LN(x + r); dbl=1: LN2(LN1(x+r)).
// ---------------------------------------------------------------------------
__global__ __launch_bounds__(256) void ln_k(
    const float* __restrict__ x,
    const float* __restrict__ r,
    const float* __restrict__ g1, const float* __restrict__ b1,
    const float* __restrict__ g2, const float* __restrict__ b2,
    float* __restrict__ out, int nrows, int dbl)
{
    const int row = blockIdx.x * 4 + (threadIdx.x >> 6);
    if (row >= nrows) return;
    const int lane = threadIdx.x & 63;

    const float* X = x + (long)row * DD;
    const float* R = r + (long)row * DD;
    float y[8];
    {
        float4 a = *(const float4*)&X[lane * 4];
        float4 c = *(const float4*)&X[256 + lane * 4];
        float4 ra = *(const float4*)&R[lane * 4];
        float4 rc = *(const float4*)&R[256 + lane * 4];
        y[0] = a.x + ra.x; y[1] = a.y + ra.y; y[2] = a.z + ra.z; y[3] = a.w + ra.w;
        y[4] = c.x + rc.x; y[5] = c.y + rc.y; y[6] = c.z + rc.z; y[7] = c.w + rc.w;
    }
    float sum = 0.f, sq = 0.f;
    #pragma unroll
    for (int i = 0; i < 8; ++i) { sum += y[i]; sq = fmaf(y[i], y[i], sq); }
    #pragma unroll
    for (int off = 32; off; off >>= 1) {
        sum += __shfl_xor(sum, off);
        sq  += __shfl_xor(sq, off);
    }
    float mean = sum * (1.f / 512.f);
    float var  = sq * (1.f / 512.f) - mean * mean;
    float rstd = rsqrtf(var + 1e-5f);
    {
        float4 ga = *(const float4*)&g1[lane * 4];
        float4 gc = *(const float4*)&g1[256 + lane * 4];
        float4 ba = *(const float4*)&b1[lane * 4];
        float4 bc = *(const float4*)&b1[256 + lane * 4];
        float gs[8] = {ga.x, ga.y, ga.z, ga.w, gc.x, gc.y, gc.z, gc.w};
        float bs[8] = {ba.x, ba.y, ba.z, ba.w, bc.x, bc.y, bc.z, bc.w};
        #pragma unroll
        for (int i = 0; i < 8; ++i) y[i] = fmaf((y[i] - mean) * rstd, gs[i], bs[i]);
    }
    if (dbl) {
        float sum2 = 0.f, sq2 = 0.f;
        #pragma unroll
        for (int i = 0; i < 8; ++i) { sum2 += y[i]; sq2 = fmaf(y[i], y[i], sq2); }
        #pragma unroll
        for (int off = 32; off; off >>= 1) {
            sum2 += __shfl_xor(sum2, off);
            sq2  += __shfl_xor(sq2, off);
        }
        float mean2 = sum2 * (1.f / 512.f);
        float var2  = sq2 * (1.f / 512.f) - mean2 * mean2;
        float rstd2 = rsqrtf(var2 + 1e-5f);
        float4 ga = *(const float4*)&g2[lane * 4];
        float4 gc = *(const float4*)&g2[256 + lane * 4];
        float4 ba = *(const float4*)&b2[lane * 4];
        float4 bc = *(const float4*)&b2[256 + lane * 4];
        float gs[8] = {ga.x, ga.y, ga.z, ga.w, gc.x, gc.y, gc.z, gc.w};
        float bs[8] = {ba.x, ba.y, ba.z, ba.w, bc.x, bc.y, bc.z, bc.w};
        #pragma unroll
        for (int i = 0; i < 8; ++i) y[i] = fmaf((y[i] - mean2) * rstd2, gs[i], bs[i]);
    }
    float* O = out + (long)row * DD;
    *(float4*)&O[lane * 4] = make_float4(y[0], y[1], y[2], y[3]);
    *(float4*)&O[256 + lane * 4] = make_float4(y[4], y[5], y[6], y[7]);
}

// ===========================================================================
// DECODE KERNELS — block per DROWS batch rows, 512 threads.
// All weight reads go through pre-TRANSPOSED WT[K][N]: thread j reads
// WT[k*N + j] -> fully coalesced across the wave; sx[k] is an LDS broadcast.
// ===========================================================================

// qkv projection of current token + KV-cache scatter. WT: [512][1536]
__global__ __launch_bounds__(512) void dec_qkv_k(
    const float* __restrict__ tgt, const float* __restrict__ WT,
    const float* __restrict__ bias, float* __restrict__ qbuf,
    float* __restrict__ kc, float* __restrict__ vc, int t)
{
    const int b0 = blockIdx.x * DROWS;
    const int j  = threadIdx.x;            // 0..511
    __shared__ float sx[DROWS][DD];
    #pragma unroll
    for (int r = 0; r < DROWS; ++r)
        sx[r][j] = tgt[((long)(b0 + r) * TCAP + t) * DD + j];
    __syncthreads();

    float a[3][DROWS];
    #pragma unroll
    for (int c = 0; c < 3; ++c) { a[c][0] = 0.f; a[c][1] = 0.f; }

    #pragma unroll 4
    for (int k = 0; k < DD; ++k) {
        float x0 = sx[0][k], x1 = sx[1][k];
        const float* wr = &WT[(long)k * (3 * DD) + j];
        float w0 = wr[0], w1 = wr[DD], w2 = wr[2 * DD];
        a[0][0] = fmaf(x0, w0, a[0][0]); a[0][1] = fmaf(x1, w0, a[0][1]);
        a[1][0] = fmaf(x0, w1, a[1][0]); a[1][1] = fmaf(x1, w1, a[1][1]);
        a[2][0] = fmaf(x0, w2, a[2][0]); a[2][1] = fmaf(x1, w2, a[2][1]);
    }

    const int h = j >> 6, d = j & 63;
    #pragma unroll
    for (int c = 0; c < 3; ++c) {
        float bv = bias[c * DD + j];
        float v0 = a[c][0] + bv, v1 = a[c][1] + bv;
        if (c == 0) {
            qbuf[(b0 + 0) * DD + j] = v0;
            qbuf[(b0 + 1) * DD + j] = v1;
        } else {
            float* cache = (c == 1) ? kc : vc;
            cache[(((b0 + 0) * NH + h) * TCAP + t) * DH + d] = v0;
            cache[(((b0 + 1) * NH + h) * TCAP + t) * DH + d] = v1;
        }
    }
}

// Decode self-attention with KV cache. 1 wave per (b,h). L = t+1 keys.
__global__ __launch_bounds__(64) void dec_sa_k(
    const float* __restrict__ qbuf, const float* __restrict__ kc,
    const float* __restrict__ vc, float* __restrict__ out, int t)
{
    const int bh = blockIdx.x;
    const int b = bh >> 3, h = bh & 7;
    const int lane = threadIdx.x;
    const int L = t + 1;

    __shared__ float sq[64];
    __shared__ float sp[64];

    sq[lane] = qbuf[b * DD + h * DH + lane];
    __syncthreads();

    const float* K = kc + (long)bh * TCAP * DH;
    float s = -1e30f;
    if (lane < L) {
        float acc = 0.f;
        #pragma unroll
        for (int d = 0; d < 64; d += 4) {
            float4 kr = *(const float4*)&K[lane * 64 + d];
            acc = fmaf(sq[d], kr.x, acc); acc = fmaf(sq[d + 1], kr.y, acc);
            acc = fmaf(sq[d + 2], kr.z, acc); acc = fmaf(sq[d + 3], kr.w, acc);
        }
        s = acc * 0.125f;
    }
    float mx = s;
    #pragma unroll
    for (int off = 32; off; off >>= 1) mx = fmaxf(mx, __shfl_xor(mx, off));
    float p = (lane < L) ? __expf(s - mx) : 0.f;
    float sum = p;
    #pragma unroll
    for (int off = 32; off; off >>= 1) sum += __shfl_xor(sum, off);
    sp[lane] = p;
    __syncthreads();

    const float* V = vc + (long)bh * TCAP * DH;
    float o = 0.f;
    for (int kk = 0; kk < L; ++kk) o = fmaf(sp[kk], V[kk * 64 + lane], o);
    out[b * DD + h * DH + lane] = o / sum;
}

// sa out-proj (WTo [512][512]) + residual + LN -> u ; caq = u @ Wq^T (WTq).
__global__ __launch_bounds__(512) void dec_saproj_k(
    const float* __restrict__ sao, const float* __restrict__ WTo,
    const float* __restrict__ bo, const float* __restrict__ tgt, int t,
    const float* __restrict__ g1, const float* __restrict__ b1,
    const float* __restrict__ WTq, const float* __restrict__ bq,
    float* __restrict__ u, float* __restrict__ caq)
{
    const int b0 = blockIdx.x * DROWS;
    const int j = threadIdx.x;
    const int w = j >> 6, lane = j & 63;
    __shared__ float sx[DROWS][DD];
    __shared__ float su[DROWS][DD];
    __shared__ float red[DROWS][16];

    #pragma unroll
    for (int r = 0; r < DROWS; ++r) sx[r][j] = sao[(b0 + r) * DD + j];
    __syncthreads();

    float acc[DROWS] = {0.f, 0.f};
    #pragma unroll 4
    for (int k = 0; k < DD; ++k) {
        float wv = WTo[(long)k * DD + j];
        acc[0] = fmaf(sx[0][k], wv, acc[0]);
        acc[1] = fmaf(sx[1][k], wv, acc[1]);
    }
    #pragma unroll
    for (int r = 0; r < DROWS; ++r)
        acc[r] += bo[j] + tgt[((long)(b0 + r) * TCAP + t) * DD + j];

    #pragma unroll
    for (int r = 0; r < DROWS; ++r) {
        float s1 = acc[r], s2 = acc[r] * acc[r];
        #pragma unroll
        for (int off = 32; off; off >>= 1) {
            s1 += __shfl_xor(s1, off); s2 += __shfl_xor(s2, off);
        }
        if (lane == 0) { red[r][w] = s1; red[r][8 + w] = s2; }
    }
    __syncthreads();
    #pragma unroll
    for (int r = 0; r < DROWS; ++r) {
        float sum = 0.f, sq = 0.f;
        #pragma unroll
        for (int i = 0; i < 8; ++i) { sum += red[r][i]; sq += red[r][8 + i]; }
        float mean = sum * (1.f / 512.f);
        float var  = sq * (1.f / 512.f) - mean * mean;
        float rstd = rsqrtf(var + 1e-5f);
        float uv = fmaf((acc[r] - mean) * rstd, g1[j], b1[j]);
        su[r][j] = uv;
        u[(b0 + r) * DD + j] = uv;
    }
    __syncthreads();

    float q0 = 0.f, q1 = 0.f;
    #pragma unroll 4
    for (int k = 0; k < DD; ++k) {
        float wv = WTq[(long)k * DD + j];
        q0 = fmaf(su[0][k], wv, q0);
        q1 = fmaf(su[1][k], wv, q1);
    }
    float bv = bq[j];
    caq[(b0 + 0) * DD + j] = q0 + bv;
    caq[(b0 + 1) * DD + j] = q1 + bv;
}

// Decode cross-attention over mem (256 keys). 256 threads per (b,h).
__global__ __launch_bounds__(256) void dec_ca_k(
    const float* __restrict__ caq, const float* __restrict__ mk,
    const float* __restrict__ mv, float* __restrict__ out)
{
    const int bh = blockIdx.x;
    const int b = bh >> 3, h = bh & 7;
    const int tid = threadIdx.x;

    __shared__ float sq[64];
    __shared__ float sp[256];
    __shared__ float red[8];
    __shared__ float so[4][64];

    if (tid < 64) sq[tid] = caq[b * DD + h * DH + tid];
    __syncthreads();

    const float* K = mk + (long)bh * SS * DH;
    float acc = 0.f;
    #pragma unroll
    for (int d = 0; d < 64; d += 4) {
        float4 kr = *(const float4*)&K[tid * 64 + d];
        acc = fmaf(sq[d], kr.x, acc); acc = fmaf(sq[d + 1], kr.y, acc);
        acc = fmaf(sq[d + 2], kr.z, acc); acc = fmaf(sq[d + 3], kr.w, acc);
    }
    float s = acc * 0.125f;

    float mx = s;
    #pragma unroll
    for (int off = 32; off; off >>= 1) mx = fmaxf(mx, __shfl_xor(mx, off));
    const int w = tid >> 6;
    if ((tid & 63) == 0) red[w] = mx;
    __syncthreads();
    mx = fmaxf(fmaxf(red[0], red[1]), fmaxf(red[2], red[3]));

    float p = __expf(s - mx);
    sp[tid] = p;
    float sum = p;
    #pragma unroll
    for (int off = 32; off; off >>= 1) sum += __shfl_xor(sum, off);
    if ((tid & 63) == 0) red[4 + w] = sum;
    __syncthreads();
    sum = red[4] + red[5] + red[6] + red[7];

    const float* V = mv + (long)bh * SS * DH;
    const int d = tid & 63;
    float o = 0.f;
    for (int kk = 0; kk < 64; ++kk) {
        int krow = w * 64 + kk;
        o = fmaf(sp[krow], V[krow * 64 + d], o);
    }
    so[w][d] = o;
    __syncthreads();
    if (tid < 64) {
        float rslt = (so[0][tid] + so[1][tid] + so[2][tid] + so[3][tid]) / sum;
        out[b * DD + h * DH + tid] = rslt;
    }
}

// ca out-proj (WTo) + residual(u) + LN -> su2 ; FF1(WT1 [512][2048]) + relu ;
// FF2(WT2 [2048][512]) + residual(su2) + LN + final LN -> tgt[:, t+1, :].
__global__ __launch_bounds__(512) void dec_tail_k(
    const float* __restrict__ cao, const float* __restrict__ WTo,
    const float* __restrict__ bo, const float* __restrict__ u,
    const float* __restrict__ g2, const float* __restrict__ b2,
    const float* __restrict__ WT1, const float* __restrict__ bb1,
    const float* __restrict__ WT2, const float* __restrict__ bb2,
    const float* __restrict__ g3, const float* __restrict__ b3,
    const float* __restrict__ gn, const float* __restrict__ bn,
    float* __restrict__ tgt, int t)
{
    const int b0 = blockIdx.x * DROWS;
    const int j = threadIdx.x;
    const int w = j >> 6, lane = j & 63;
    __shared__ float sx[DROWS][DD];
    __shared__ float su2[DROWS][DD];
    __shared__ float sf[DROWS][DFF];
    __shared__ float red[DROWS][16];

    #pragma unroll
    for (int r = 0; r < DROWS; ++r) sx[r][j] = cao[(b0 + r) * DD + j];
    __syncthreads();

    // ca out-proj + residual u
    float acc[DROWS] = {0.f, 0.f};
    #pragma unroll 4
    for (int k = 0; k < DD; ++k) {
        float wv = WTo[(long)k * DD + j];
        acc[0] = fmaf(sx[0][k], wv, acc[0]);
        acc[1] = fmaf(sx[1][k], wv, acc[1]);
    }
    #pragma unroll
    for (int r = 0; r < DROWS; ++r)
        acc[r] += bo[j] + u[(b0 + r) * DD + j];

    // LN(g2,b2) -> su2
    #pragma unroll
    for (int r = 0; r < DROWS; ++r) {
        float s1 = acc[r], s2 = acc[r] * acc[r];
        #pragma unroll
        for (int off = 32; off; off >>= 1) {
            s1 += __shfl_xor(s1, off); s2 += __shfl_xor(s2, off);
        }
        if (lane == 0) { red[r][w] = s1; red[r][8 + w] = s2; }
    }
    __syncthreads();
    #pragma unroll
    for (int r = 0; r < DROWS; ++r) {
        float sum = 0.f, sq = 0.f;
        #pragma unroll
        for (int i = 0; i < 8; ++i) { sum += red[r][i]; sq += red[r][8 + i]; }
        float mean = sum * (1.f / 512.f);
        float var  = sq * (1.f / 512.f) - mean * mean;
        float rstd = rsqrtf(var + 1e-5f);
        su2[r][j] = fmaf((acc[r] - mean) * rstd, g2[j], b2[j]);
    }
    __syncthreads();

    // FF1 + relu -> sf (4 cols per thread; coalesced WT1 reads)
    {
        float f[4][DROWS];
        #pragma unroll
        for (int c = 0; c < 4; ++c) { f[c][0] = 0.f; f[c][1] = 0.f; }
        #pragma unroll 4
        for (int k = 0; k < DD; ++k) {
            float x0 = su2[0][k], x1 = su2[1][k];
            const float* wr = &WT1[(long)k * DFF + j];
            #pragma unroll
            for (int c = 0; c < 4; ++c) {
                float wv = wr[c * DD];
                f[c][0] = fmaf(x0, wv, f[c][0]);
                f[c][1] = fmaf(x1, wv, f[c][1]);
            }
        }
        #pragma unroll
        for (int c = 0; c < 4; ++c) {
            float bv = bb1[c * DD + j];
            sf[0][c * DD + j] = fmaxf(f[c][0] + bv, 0.f);
            sf[1][c * DD + j] = fmaxf(f[c][1] + bv, 0.f);
        }
    }
    __syncthreads();

    // FF2 + residual su2
    float a2[DROWS] = {0.f, 0.f};
    #pragma unroll 4
    for (int k = 0; k < DFF; ++k) {
        float wv = WT2[(long)k * DD + j];
        a2[0] = fmaf(sf[0][k], wv, a2[0]);
        a2[1] = fmaf(sf[1][k], wv, a2[1]);
    }
    #pragma unroll
    for (int r = 0; r < DROWS; ++r)
        a2[r] += bb2[j] + su2[r][j];

    // LN(g3,b3)
    float y[DROWS];
    __syncthreads();   // red safe to reuse
    #pragma unroll
    for (int r = 0; r < DROWS; ++r) {
        float s1 = a2[r], s2 = a2[r] * a2[r];
        #pragma unroll
        for (int off = 32; off; off >>= 1) {
            s1 += __shfl_xor(s1, off); s2 += __shfl_xor(s2, off);
        }
        if (lane == 0) { red[r][w] = s1; red[r][8 + w] = s2; }
    }
    __syncthreads();
    #pragma unroll
    for (int r = 0; r < DROWS; ++r) {
        float sum = 0.f, sq = 0.f;
        #pragma unroll
        for (int i = 0; i < 8; ++i) { sum += red[r][i]; sq += red[r][8 + i]; }
        float mean = sum * (1.f / 512.f);
        float var  = sq * (1.f / 512.f) - mean * mean;
        float rstd = rsqrtf(var + 1e-5f);
        y[r] = fmaf((a2[r] - mean) * rstd, g3[j], b3[j]);
    }
    // final LN(gn,bn)
    __syncthreads();
    #pragma unroll
    for (int r = 0; r < DROWS; ++r) {
        float s1 = y[r], s2 = y[r] * y[r];
        #pragma unroll
        for (int off = 32; off; off >>= 1) {
            s1 += __shfl_xor(s1, off); s2 += __shfl_xor(s2, off);
        }
        if (lane == 0) { red[r][w] = s1; red[r][8 + w] = s2; }
    }
    __syncthreads();
    #pragma unroll
    for (int r = 0; r < DROWS; ++r) {
        float sum = 0.f, sq = 0.f;
        #pragma unroll
        for (int i = 0; i < 8; ++i) { sum += red[r][i]; sq += red[r][8 + i]; }
        float mean = sum * (1.f / 512.f);
        float var  = sq * (1.f / 512.f) - mean * mean;
        float rstd = rsqrtf(var + 1e-5f);
        float out = fmaf((y[r] - mean) * rstd, gn[j], bn[j]);
        tgt[((long)(b0 + r) * TCAP + t + 1) * DD + j] = out;
    }
}

// tgt[:,0,:] = start_token
__global__ __launch_bounds__(256) void init_tgt_k(
    const float* __restrict__ start, float* __restrict__ tgt)
{
    int idx = blockIdx.x * 256 + threadIdx.x;
    if (idx >= BB * DD) return;
    int b = idx >> 9, d = idx & 511;
    tgt[(long)b * TCAP * DD + d] = start[d];
}

// packed[b*16+s][d] = tgt[b][s+1][d]
__global__ __launch_bounds__(256) void pack_k(
    const float* __restrict__ tgt, float* __restrict__ packed)
{
    int idx = blockIdx.x * 256 + threadIdx.x;
    if (idx >= BB * TLEN * DD) return;
    int d = idx & 511;
    int r = idx >> 9;
    int b = r >> 4, s = r & 15;
    packed[idx] = tgt[((long)b * TCAP + s + 1) * DD + d];
}

// ---------------------------------------------------------------------------
extern "C" void kernel_launch(void* const* d_in, const int* in_sizes, int n_in,
                              void* d_out, int out_size, void* d_ws, size_t ws_size,
                              hipStream_t stream) {
    const float* x          = (const float*)d_in[0];
    const float* W_in       = (const float*)d_in[1];
    const float* b_in       = (const float*)d_in[2];
    const float* start_tok  = (const float*)d_in[3];
    const float* enc_qkv_w  = (const float*)d_in[4];
    const float* enc_qkv_b  = (const float*)d_in[5];
    const float* enc_out_w  = (const float*)d_in[6];
    const float* enc_out_b  = (const float*)d_in[7];
    const float* enc_ln1_g  = (const float*)d_in[8];
    const float* enc_ln1_b  = (const float*)d_in[9];
    const float* enc_ff1_w  = (const float*)d_in[10];
    const float* enc_ff1_b  = (const float*)d_in[11];
    const float* enc_ff2_w  = (const float*)d_in[12];
    const float* enc_ff2_b  = (const float*)d_in[13];
    const float* enc_ln2_g  = (const float*)d_in[14];
    const float* enc_ln2_b  = (const float*)d_in[15];
    const float* enc_norm_g = (const float*)d_in[16];
    const float* enc_norm_b = (const float*)d_in[17];
    const float* dsa_qkv_w  = (const float*)d_in[18];
    const float* dsa_qkv_b  = (const float*)d_in[19];
    const float* dsa_out_w  = (const float*)d_in[20];
    const float* dsa_out_b  = (const float*)d_in[21];
    const float* dln1_g     = (const float*)d_in[22];
    const float* dln1_b     = (const float*)d_in[23];
    const float* dca_qkv_w  = (const float*)d_in[24];
    const float* dca_qkv_b  = (const float*)d_in[25];
    const float* dca_out_w  = (const float*)d_in[26];
    const float* dca_out_b  = (const float*)d_in[27];
    const float* dln2_g     = (const float*)d_in[28];
    const float* dln2_b     = (const float*)d_in[29];
    const float* dff1_w     = (const float*)d_in[30];
    const float* dff1_b     = (const float*)d_in[31];
    const float* dff2_w     = (const float*)d_in[32];
    const float* dff2_b     = (const float*)d_in[33];
    const float* dln3_g     = (const float*)d_in[34];
    const float* dln3_b     = (const float*)d_in[35];
    const float* dnorm_g    = (const float*)d_in[36];
    const float* dnorm_b    = (const float*)d_in[37];
    const float* W_out      = (const float*)d_in[38];
    const float* b_out      = (const float*)d_in[39];
    // d_in[40] = description_length (fixed 16; hardcoded)

    float* ws = (float*)d_ws;
    const size_t A = AREG;
    float* buf0 = ws;                 // src -> mem
    float* buf1 = ws + 1 * A;         // q   -> tmp -> tmp2
    float* buf2 = ws + 2 * A;         // k   -> h1  -> memK
    float* buf3 = ws + 3 * A;         // v   -> ff(lo)-> memV
    float* buf4 = ws + 4 * A;         // attn-> ff(hi)
    float* src  = buf0;
    float* qh   = buf1;
    float* attn = buf4;
    float* tmp  = buf1;
    float* h1   = buf2;
    float* ffbuf= buf3;               // [8192, 2048] = 2A (buf3..buf4)
    float* tmp2 = buf1;
    float* mem  = buf0;
    float* memK = buf2;               // memV at buf3 (mode-2 which*A)

    float* sb     = ws + 5 * A;
    float* tgt    = sb;                      // BB*TCAP*DD = 557056
    float* kcache = tgt + BH17;              // 557056
    float* vcache = kcache + BH17;           // 557056
    float* qbuf   = vcache + BH17;
    float* sao    = qbuf + 32768;
    float* u      = sao + 32768;
    float* caq    = u + 32768;
    float* cao    = caq + 32768;
    float* packed = cao + 32768;             // 524288
    // pre-transposed decode weights (WT[K][N])
    float* wt_qkv = packed + 524288;         // 512 x 1536 = 786432
    float* wt_sao = wt_qkv + 786432;         // 512 x 512  = 262144
    float* wt_caq = wt_sao + 262144;         // 512 x 512
    float* wt_cao = wt_caq + 262144;         // 512 x 512
    float* wt_ff1 = wt_cao + 262144;         // 512 x 2048 = 1048576
    float* wt_ff2 = wt_ff1 + 1048576;        // 2048 x 512 = 1048576

    auto gemm = [&](const float* Ap, int lda, const float* Wp, const float* bp,
                    float* outp, int M, int N, int K, int mode) {
        dim3 g((M + BM - 1) / BM, N / BN);
        gemm_k<<<g, 256, 0, stream>>>(Ap, lda, Wp, bp, outp, M, N, K, mode);
    };
    auto ln = [&](const float* xp, const float* rp,
                  const float* g1, const float* b1, const float* g2, const float* b2,
                  float* op, int nrows, int dbl) {
        ln_k<<<(nrows + 3) / 4, 256, 0, stream>>>(xp, rp, g1, b1, g2, b2, op, nrows, dbl);
    };
    auto tr = [&](const float* Wp, float* WTp, int N, int K) {
        tr_k<<<dim3(N / 32, K / 32), 256, 0, stream>>>(Wp, WTp, N, K);
    };

    const int MS = BB * SS;  // 16384

    // ---- One-time decode weight transposes (graph-safe, every call) ----
    tr(dsa_qkv_w, wt_qkv, 3 * DD, DD);
    tr(dsa_out_w, wt_sao, DD, DD);
    tr(dca_qkv_w, wt_caq, DD, DD);     // q-part = first 512 rows
    tr(dca_out_w, wt_cao, DD, DD);
    tr(dff1_w,    wt_ff1, DFF, DD);
    tr(dff2_w,    wt_ff2, DD, DFF);

    // ---- Encoder ----
    gemm(x, DIN, W_in, b_in, src, MS, DD, DIN, 0);
    gemm(src, DD, enc_qkv_w, enc_qkv_b, qh, MS, 3 * DD, DD, 2);
    enc_attn_k<<<BB * NH, 256, 0, stream>>>(buf1, buf2, buf3, attn);
    gemm(attn, DD, enc_out_w, enc_out_b, tmp, MS, DD, DD, 0);
    ln(tmp, src, enc_ln1_g, enc_ln1_b, nullptr, nullptr, h1, MS, 0);
    for (int c = 0; c < 2; ++c) {
        int roff = c * (MS / 2);
        gemm(h1 + (long)roff * DD, DD, enc_ff1_w, enc_ff1_b, ffbuf, MS / 2, DFF, DD, 1);
        gemm(ffbuf, DFF, enc_ff2_w, enc_ff2_b, tmp2 + (long)roff * DD, MS / 2, DD, DFF, 0);
    }
    ln(tmp2, h1, enc_ln2_g, enc_ln2_b, enc_norm_g, enc_norm_b, mem, MS, 1);
    gemm(mem, DD, dca_qkv_w + 512 * 512, dca_qkv_b + 512, memK, MS, 2 * DD, DD, 2);

    // ---- Decoder (KV-cached, fused row-block kernels, coalesced WT) ----
    init_tgt_k<<<(BB * DD + 255) / 256, 256, 0, stream>>>(start_tok, tgt);

    const int DG = BB / DROWS;  // 32 blocks
    for (int t = 0; t < TLEN; ++t) {
        dec_qkv_k<<<DG, 512, 0, stream>>>(tgt, wt_qkv, dsa_qkv_b, qbuf, kcache, vcache, t);
        dec_sa_k<<<BB * NH, 64, 0, stream>>>(qbuf, kcache, vcache, sao, t);
        dec_saproj_k<<<DG, 512, 0, stream>>>(sao, wt_sao, dsa_out_b, tgt, t,
                                             dln1_g, dln1_b, wt_caq, dca_qkv_b, u, caq);
        dec_ca_k<<<BB * NH, 256, 0, stream>>>(caq, memK, memK + A, cao);
        dec_tail_k<<<DG, 512, 0, stream>>>(cao, wt_cao, dca_out_b, u,
                                           dln2_g, dln2_b, wt_ff1, dff1_b,
                                           wt_ff2, dff2_b, dln3_g, dln3_b,
                                           dnorm_g, dnorm_b, tgt, t);
    }

    // ---- Output projection ----
    pack_k<<<(BB * TLEN * DD + 255) / 256, 256, 0, stream>>>(tgt, packed);
    gemm(packed, DD, W_out, b_out, (float*)d_out, BB * TLEN, DD, DD, 0);
}

// Round 6
// 5734.795 us; speedup vs baseline: 2.1913x; 1.4625x over previous
//
#include <hip/hip_runtime.h>
#include <hip/hip_bf16.h>

// Problem constants (from setup_inputs)
#define BB   64      // batch
#define SS   256     // src sequence (16*16)
#define DD   512     // model dim
#define DFF  2048
#define DIN  256
#define NH   8
#define DH   64
#define TLEN 16      // description_length (fixed by setup)
#define TCAP 17      // tgt capacity (start token + 16)

constexpr size_t AREG = (size_t)BB * SS * DD;   // 8,388,608 floats per [B,S,D] buffer
constexpr int    BH17 = BB * NH * TCAP * DH;    // 557,056

// ---------------------------------------------------------------------------
// Encoder fp32 GEMM: C[M,N] = A[M,K] @ W[N,K]^T + bias. (unchanged)
// ---------------------------------------------------------------------------
#define BM 128
#define BN 128
#define BK 16

__global__ __launch_bounds__(256) void gemm_k(
    const float* __restrict__ A, int lda,
    const float* __restrict__ W,
    const float* __restrict__ bias,
    float* __restrict__ out,
    int M, int N, int K, int mode)
{
    __shared__ float sA[BK][BM + 4];
    __shared__ float sB[BK][BN + 4];

    const int row0 = blockIdx.x * BM;
    const int col0 = blockIdx.y * BN;
    const int tid  = threadIdx.x;
    const int tx   = tid & 15;
    const int ty   = tid >> 4;

    float acc[8][8];
    #pragma unroll
    for (int i = 0; i < 8; ++i)
        #pragma unroll
        for (int j = 0; j < 8; ++j) acc[i][j] = 0.f;

    const int ar  = tid >> 2;
    const int ac4 = (tid & 3) * 4;

    float4 pa[2], pb[2];
    auto load_tiles = [&](int k0) {
        #pragma unroll
        for (int i = 0; i < 2; ++i) {
            int grow = row0 + ar + i * 64;
            pa[i] = make_float4(0.f, 0.f, 0.f, 0.f);
            if (grow < M) pa[i] = *(const float4*)&A[(long)grow * lda + k0 + ac4];
            pb[i] = *(const float4*)&W[(long)(col0 + ar + i * 64) * K + k0 + ac4];
        }
    };

    load_tiles(0);
    for (int k0 = 0; k0 < K; k0 += BK) {
        #pragma unroll
        for (int i = 0; i < 2; ++i) {
            int r = ar + i * 64;
            sA[ac4 + 0][r] = pa[i].x; sA[ac4 + 1][r] = pa[i].y;
            sA[ac4 + 2][r] = pa[i].z; sA[ac4 + 3][r] = pa[i].w;
            sB[ac4 + 0][r] = pb[i].x; sB[ac4 + 1][r] = pb[i].y;
            sB[ac4 + 2][r] = pb[i].z; sB[ac4 + 3][r] = pb[i].w;
        }
        __syncthreads();

        if (k0 + BK < K) load_tiles(k0 + BK);

        #pragma unroll
        for (int k = 0; k < BK; ++k) {
            float4 a0 = *(const float4*)&sA[k][ty * 8];
            float4 a1 = *(const float4*)&sA[k][ty * 8 + 4];
            float4 b0 = *(const float4*)&sB[k][tx * 8];
            float4 b1 = *(const float4*)&sB[k][tx * 8 + 4];
            float a[8] = {a0.x, a0.y, a0.z, a0.w, a1.x, a1.y, a1.z, a1.w};
            float b[8] = {b0.x, b0.y, b0.z, b0.w, b1.x, b1.y, b1.z, b1.w};
            #pragma unroll
            for (int i = 0; i < 8; ++i)
                #pragma unroll
                for (int j = 0; j < 8; ++j)
                    acc[i][j] = fmaf(a[i], b[j], acc[i][j]);
        }
        __syncthreads();
    }

    const int gcol0 = col0 + tx * 8;
    float4 bb0 = *(const float4*)&bias[gcol0];
    float4 bb1 = *(const float4*)&bias[gcol0 + 4];
    float bs[8] = {bb0.x, bb0.y, bb0.z, bb0.w, bb1.x, bb1.y, bb1.z, bb1.w};
    #pragma unroll
    for (int i = 0; i < 8; ++i) {
        int grow = row0 + ty * 8 + i;
        if (grow >= M) continue;
        float v[8];
        #pragma unroll
        for (int j = 0; j < 8; ++j) {
            v[j] = acc[i][j] + bs[j];
            if (mode == 1) v[j] = fmaxf(v[j], 0.f);
        }
        float4 v0 = make_float4(v[0], v[1], v[2], v[3]);
        float4 v1 = make_float4(v[4], v[5], v[6], v[7]);
        if (mode <= 1) {
            float* p = &out[(long)grow * N + gcol0];
            *(float4*)p = v0; *(float4*)(p + 4) = v1;
        } else { // mode 2
            int b = grow >> 8, s = grow & 255;
            int which = gcol0 >> 9;
            int h = (gcol0 >> 6) & 7, d = gcol0 & 63;
            float* p = &out[(long)which * AREG + (((b * 8 + h) * 256 + s) * 64 + d)];
            *(float4*)p = v0; *(float4*)(p + 4) = v1;
        }
    }
}

// ---------------------------------------------------------------------------
// Tiled transpose: WT[k][n] = W[n][k]. N, K multiples of 32. (unchanged)
// ---------------------------------------------------------------------------
__global__ __launch_bounds__(256) void tr_k(
    const float* __restrict__ W, float* __restrict__ WT, int N, int K)
{
    __shared__ float tile[32][33];
    const int n0 = blockIdx.x * 32, k0 = blockIdx.y * 32;
    const int tx = threadIdx.x & 31, ty = threadIdx.x >> 5;
    #pragma unroll
    for (int i = 0; i < 4; ++i)
        tile[ty + i * 8][tx] = W[(long)(n0 + ty + i * 8) * K + k0 + tx];
    __syncthreads();
    #pragma unroll
    for (int i = 0; i < 4; ++i)
        WT[(long)(k0 + ty + i * 8) * N + n0 + tx] = tile[tx][ty + i * 8];
}

// ---------------------------------------------------------------------------
// Encoder fused attention (unchanged)
// ---------------------------------------------------------------------------
__global__ __launch_bounds__(256) void enc_attn_k(
    const float* __restrict__ q, const float* __restrict__ k,
    const float* __restrict__ v, float* __restrict__ out)
{
    const int bh = blockIdx.x;
    const int b = bh >> 3, h = bh & 7;
    const float* Q = q + (long)bh * SS * DH;
    const float* Kp = k + (long)bh * SS * DH;
    const float* Vp = v + (long)bh * SS * DH;
    const int t = threadIdx.x;

    __shared__ float4 sK[16][16];
    __shared__ float4 sV[16][16];

    float4 q4[16];
    #pragma unroll
    for (int i = 0; i < 16; ++i) q4[i] = *(const float4*)&Q[t * 64 + i * 4];

    float4 o4[16];
    #pragma unroll
    for (int i = 0; i < 16; ++i) o4[i] = make_float4(0.f, 0.f, 0.f, 0.f);
    float m = -1e30f, l = 0.f;

    const int r = t >> 4, c4 = t & 15;
    for (int c = 0; c < 16; ++c) {
        sK[r][c4] = *(const float4*)&Kp[(c * 16 + r) * 64 + c4 * 4];
        sV[r][c4] = *(const float4*)&Vp[(c * 16 + r) * 64 + c4 * 4];
        __syncthreads();

        float sc[16];
        #pragma unroll
        for (int kk = 0; kk < 16; ++kk) {
            float s = 0.f;
            #pragma unroll
            for (int i = 0; i < 16; ++i) {
                float4 kv = sK[kk][i];
                s = fmaf(q4[i].x, kv.x, s); s = fmaf(q4[i].y, kv.y, s);
                s = fmaf(q4[i].z, kv.z, s); s = fmaf(q4[i].w, kv.w, s);
            }
            sc[kk] = s * 0.125f;
        }
        float cm = sc[0];
        #pragma unroll
        for (int kk = 1; kk < 16; ++kk) cm = fmaxf(cm, sc[kk]);
        float mn = fmaxf(m, cm);
        float alpha = __expf(m - mn);
        float ps[16]; float psum = 0.f;
        #pragma unroll
        for (int kk = 0; kk < 16; ++kk) { ps[kk] = __expf(sc[kk] - mn); psum += ps[kk]; }
        l = l * alpha + psum;
        #pragma unroll
        for (int i = 0; i < 16; ++i) {
            o4[i].x *= alpha; o4[i].y *= alpha; o4[i].z *= alpha; o4[i].w *= alpha;
        }
        #pragma unroll
        for (int kk = 0; kk < 16; ++kk) {
            float p = ps[kk];
            #pragma unroll
            for (int i = 0; i < 16; ++i) {
                float4 vv = sV[kk][i];
                o4[i].x = fmaf(p, vv.x, o4[i].x); o4[i].y = fmaf(p, vv.y, o4[i].y);
                o4[i].z = fmaf(p, vv.z, o4[i].z); o4[i].w = fmaf(p, vv.w, o4[i].w);
            }
        }
        m = mn;
        __syncthreads();
    }

    float inv = 1.f / l;
    float* O = out + ((long)(b * SS + t)) * DD + h * DH;
    #pragma unroll
    for (int i = 0; i < 16; ++i) {
        float4 v_;
        v_.x = o4[i].x * inv; v_.y = o4[i].y * inv;
        v_.z = o4[i].z * inv; v_.w = o4[i].w * inv;
        *(float4*)&O[i * 4] = v_;
    }
}

// ---------------------------------------------------------------------------
// Encoder LayerNorm (unchanged)
// ---------------------------------------------------------------------------
__global__ __launch_bounds__(256) void ln_k(
    const float* __restrict__ x,
    const float* __restrict__ r,
    const float* __restrict__ g1, const float* __restrict__ b1,
    const float* __restrict__ g2, const float* __restrict__ b2,
    float* __restrict__ out, int nrows, int dbl)
{
    const int row = blockIdx.x * 4 + (threadIdx.x >> 6);
    if (row >= nrows) return;
    const int lane = threadIdx.x & 63;

    const float* X = x + (long)row * DD;
    const float* R = r + (long)row * DD;
    float y[8];
    {
        float4 a = *(const float4*)&X[lane * 4];
        float4 c = *(const float4*)&X[256 + lane * 4];
        float4 ra = *(const float4*)&R[lane * 4];
        float4 rc = *(const float4*)&R[256 + lane * 4];
        y[0] = a.x + ra.x; y[1] = a.y + ra.y; y[2] = a.z + ra.z; y[3] = a.w + ra.w;
        y[4] = c.x + rc.x; y[5] = c.y + rc.y; y[6] = c.z + rc.z; y[7] = c.w + rc.w;
    }
    float sum = 0.f, sq = 0.f;
    #pragma unroll
    for (int i = 0; i < 8; ++i) { sum += y[i]; sq = fmaf(y[i], y[i], sq); }
    #pragma unroll
    for (int off = 32; off; off >>= 1) {
        sum += __shfl_xor(sum, off);
        sq  += __shfl_xor(sq, off);
    }
    float mean = sum * (1.f / 512.f);
    float var  = sq * (1.f / 512.f) - mean * mean;
    float rstd = rsqrtf(var + 1e-5f);
    {
        float4 ga = *(const float4*)&g1[lane * 4];
        float4 gc = *(const float4*)&g1[256 + lane * 4];
        float4 ba = *(const float4*)&b1[lane * 4];
        float4 bc = *(const float4*)&b1[256 + lane * 4];
        float gs[8] = {ga.x, ga.y, ga.z, ga.w, gc.x, gc.y, gc.z, gc.w};
        float bs[8] = {ba.x, ba.y, ba.z, ba.w, bc.x, bc.y, bc.z, bc.w};
        #pragma unroll
        for (int i = 0; i < 8; ++i) y[i] = fmaf((y[i] - mean) * rstd, gs[i], bs[i]);
    }
    if (dbl) {
        float sum2 = 0.f, sq2 = 0.f;
        #pragma unroll
        for (int i = 0; i < 8; ++i) { sum2 += y[i]; sq2 = fmaf(y[i], y[i], sq2); }
        #pragma unroll
        for (int off = 32; off; off >>= 1) {
            sum2 += __shfl_xor(sum2, off);
            sq2  += __shfl_xor(sq2, off);
        }
        float mean2 = sum2 * (1.f / 512.f);
        float var2  = sq2 * (1.f / 512.f) - mean2 * mean2;
        float rstd2 = rsqrtf(var2 + 1e-5f);
        float4 ga = *(const float4*)&g2[lane * 4];
        float4 gc = *(const float4*)&g2[256 + lane * 4];
        float4 ba = *(const float4*)&b2[lane * 4];
        float4 bc = *(const float4*)&b2[256 + lane * 4];
        float gs[8] = {ga.x, ga.y, ga.z, ga.w, gc.x, gc.y, gc.z, gc.w};
        float bs[8] = {ba.x, ba.y, ba.z, ba.w, bc.x, bc.y, bc.z, bc.w};
        #pragma unroll
        for (int i = 0; i < 8; ++i) y[i] = fmaf((y[i] - mean2) * rstd2, gs[i], bs[i]);
    }
    float* O = out + (long)row * DD;
    *(float4*)&O[lane * 4] = make_float4(y[0], y[1], y[2], y[3]);
    *(float4*)&O[256 + lane * 4] = make_float4(y[4], y[5], y[6], y[7]);
}

// ===========================================================================
// DECODE — column-parallel stage kernels. Weights are pre-transposed WT[K][N];
// each block owns a column slice so the weight stream is split across CUs
// (round-5 lesson: fused row-block kernels were per-CU L2-BW-bound at 62µs).
// ===========================================================================

// S1: qkv proj. 96 blocks x 256 thr; thread = one float4 of [64 x 1536] output.
__global__ __launch_bounds__(256) void dqkv_k(
    const float* __restrict__ tgt, const float* __restrict__ WT,  // [512][1536]
    const float* __restrict__ bias, float* __restrict__ qbuf,
    float* __restrict__ kc, float* __restrict__ vc, int t)
{
    const int gid = blockIdx.x * 256 + threadIdx.x;   // 0..24575
    const int r = gid / 384;
    const int q = gid % 384;
    const int col0 = q * 4;
    const float* xr = &tgt[((long)r * TCAP + t) * DD];
    float4 acc = make_float4(0.f, 0.f, 0.f, 0.f);
    #pragma unroll 8
    for (int k = 0; k < DD; ++k) {
        float xv = xr[k];
        float4 w = *(const float4*)&WT[(long)k * (3 * DD) + col0];
        acc.x = fmaf(xv, w.x, acc.x); acc.y = fmaf(xv, w.y, acc.y);
        acc.z = fmaf(xv, w.z, acc.z); acc.w = fmaf(xv, w.w, acc.w);
    }
    float4 bv = *(const float4*)&bias[col0];
    acc.x += bv.x; acc.y += bv.y; acc.z += bv.z; acc.w += bv.w;
    const int which = col0 >> 9;
    const int cc = col0 & 511;
    if (which == 0) {
        *(float4*)&qbuf[r * DD + cc] = acc;
    } else {
        const int h = cc >> 6, d = cc & 63;
        float* cache = (which == 1) ? kc : vc;
        *(float4*)&cache[(((long)r * NH + h) * TCAP + t) * DH + d] = acc;
    }
}

// S3/S6: generic 512->512 proj + bias + residual. 32 blocks x 256 thr.
__global__ __launch_bounds__(256) void dproj_k(
    const float* __restrict__ xb,           // [64][512]
    const float* __restrict__ WT,           // [512][512]
    const float* __restrict__ bias,
    const float* __restrict__ res, long res_stride,
    float* __restrict__ out)                // [64][512]
{
    const int gid = blockIdx.x * 256 + threadIdx.x;  // 0..8191
    const int r = gid >> 7;
    const int col0 = (gid & 127) * 4;
    const float* xr = &xb[r * DD];
    float4 acc = make_float4(0.f, 0.f, 0.f, 0.f);
    #pragma unroll 8
    for (int k = 0; k < DD; ++k) {
        float xv = xr[k];
        float4 w = *(const float4*)&WT[(long)k * DD + col0];
        acc.x = fmaf(xv, w.x, acc.x); acc.y = fmaf(xv, w.y, acc.y);
        acc.z = fmaf(xv, w.z, acc.z); acc.w = fmaf(xv, w.w, acc.w);
    }
    float4 bv = *(const float4*)&bias[col0];
    float4 rv = *(const float4*)&res[(long)r * res_stride + col0];
    acc.x += bv.x + rv.x; acc.y += bv.y + rv.y;
    acc.z += bv.z + rv.z; acc.w += bv.w + rv.w;
    *(float4*)&out[r * DD + col0] = acc;
}

// Decode self-attention with KV cache (unchanged). 512 blocks x 64 thr.
__global__ __launch_bounds__(64) void dec_sa_k(
    const float* __restrict__ qbuf, const float* __restrict__ kc,
    const float* __restrict__ vc, float* __restrict__ out, int t)
{
    const int bh = blockIdx.x;
    const int b = bh >> 3, h = bh & 7;
    const int lane = threadIdx.x;
    const int L = t + 1;

    __shared__ float sq[64];
    __shared__ float sp[64];

    sq[lane] = qbuf[b * DD + h * DH + lane];
    __syncthreads();

    const float* K = kc + (long)bh * TCAP * DH;
    float s = -1e30f;
    if (lane < L) {
        float acc = 0.f;
        #pragma unroll
        for (int d = 0; d < 64; d += 4) {
            float4 kr = *(const float4*)&K[lane * 64 + d];
            acc = fmaf(sq[d], kr.x, acc); acc = fmaf(sq[d + 1], kr.y, acc);
            acc = fmaf(sq[d + 2], kr.z, acc); acc = fmaf(sq[d + 3], kr.w, acc);
        }
        s = acc * 0.125f;
    }
    float mx = s;
    #pragma unroll
    for (int off = 32; off; off >>= 1) mx = fmaxf(mx, __shfl_xor(mx, off));
    float p = (lane < L) ? __expf(s - mx) : 0.f;
    float sum = p;
    #pragma unroll
    for (int off = 32; off; off >>= 1) sum += __shfl_xor(sum, off);
    sp[lane] = p;
    __syncthreads();

    const float* V = vc + (long)bh * TCAP * DH;
    float o = 0.f;
    for (int kk = 0; kk < L; ++kk) o = fmaf(sp[kk], V[kk * 64 + lane], o);
    out[b * DD + h * DH + lane] = o / sum;
}

// S4: row-block LN(upre) -> u (global + LDS) ; caq = LN @ WTq + bq. 64 blocks.
__global__ __launch_bounds__(256) void dlnproj_k(
    const float* __restrict__ upre,
    const float* __restrict__ g, const float* __restrict__ b,
    const float* __restrict__ WT, const float* __restrict__ bias,
    float* __restrict__ u, float* __restrict__ caq)
{
    const int r = blockIdx.x;
    const int tid = threadIdx.x;
    const int w = tid >> 6, lane = tid & 63;
    __shared__ float su[DD];
    __shared__ float red[16];

    float v0 = upre[r * DD + tid], v1 = upre[r * DD + 256 + tid];
    float s1 = v0 + v1, s2 = v0 * v0 + v1 * v1;
    #pragma unroll
    for (int off = 32; off; off >>= 1) { s1 += __shfl_xor(s1, off); s2 += __shfl_xor(s2, off); }
    if (lane == 0) { red[w] = s1; red[8 + w] = s2; }
    __syncthreads();
    float sum = red[0] + red[1] + red[2] + red[3];
    float sq  = red[8] + red[9] + red[10] + red[11];
    float mean = sum * (1.f / 512.f);
    float var  = sq * (1.f / 512.f) - mean * mean;
    float rstd = rsqrtf(var + 1e-5f);
    float a0 = fmaf((v0 - mean) * rstd, g[tid], b[tid]);
    float a1 = fmaf((v1 - mean) * rstd, g[tid + 256], b[tid + 256]);
    su[tid] = a0; su[tid + 256] = a1;
    u[r * DD + tid] = a0; u[r * DD + 256 + tid] = a1;
    __syncthreads();

    float q0 = 0.f, q1 = 0.f;
    #pragma unroll 8
    for (int k = 0; k < DD; ++k) {
        float xv = su[k];
        q0 = fmaf(xv, WT[(long)k * DD + tid], q0);
        q1 = fmaf(xv, WT[(long)k * DD + tid + 256], q1);
    }
    caq[r * DD + tid] = q0 + bias[tid];
    caq[r * DD + tid + 256] = q1 + bias[tid + 256];
}

// Decode cross-attention over mem (unchanged). 512 blocks x 256 thr.
__global__ __launch_bounds__(256) void dec_ca_k(
    const float* __restrict__ caq, const float* __restrict__ mk,
    const float* __restrict__ mv, float* __restrict__ out)
{
    const int bh = blockIdx.x;
    const int b = bh >> 3, h = bh & 7;
    const int tid = threadIdx.x;

    __shared__ float sq[64];
    __shared__ float sp[256];
    __shared__ float red[8];
    __shared__ float so[4][64];

    if (tid < 64) sq[tid] = caq[b * DD + h * DH + tid];
    __syncthreads();

    const float* K = mk + (long)bh * SS * DH;
    float acc = 0.f;
    #pragma unroll
    for (int d = 0; d < 64; d += 4) {
        float4 kr = *(const float4*)&K[tid * 64 + d];
        acc = fmaf(sq[d], kr.x, acc); acc = fmaf(sq[d + 1], kr.y, acc);
        acc = fmaf(sq[d + 2], kr.z, acc); acc = fmaf(sq[d + 3], kr.w, acc);
    }
    float s = acc * 0.125f;

    float mx = s;
    #pragma unroll
    for (int off = 32; off; off >>= 1) mx = fmaxf(mx, __shfl_xor(mx, off));
    const int w = tid >> 6;
    if ((tid & 63) == 0) red[w] = mx;
    __syncthreads();
    mx = fmaxf(fmaxf(red[0], red[1]), fmaxf(red[2], red[3]));

    float p = __expf(s - mx);
    sp[tid] = p;
    float sum = p;
    #pragma unroll
    for (int off = 32; off; off >>= 1) sum += __shfl_xor(sum, off);
    if ((tid & 63) == 0) red[4 + w] = sum;
    __syncthreads();
    sum = red[4] + red[5] + red[6] + red[7];

    const float* V = mv + (long)bh * SS * DH;
    const int d = tid & 63;
    float o = 0.f;
    for (int kk = 0; kk < 64; ++kk) {
        int krow = w * 64 + kk;
        o = fmaf(sp[krow], V[krow * 64 + d], o);
    }
    so[w][d] = o;
    __syncthreads();
    if (tid < 64) {
        float rslt = (so[0][tid] + so[1][tid] + so[2][tid] + so[3][tid]) / sum;
        out[b * DD + h * DH + tid] = rslt;
    }
}

// S7: row-block LN(u2pre) -> u2 (global + LDS) ; ff1+relu -> ffact. 64 blocks.
__global__ __launch_bounds__(256) void dlnff1_k(
    const float* __restrict__ u2pre,
    const float* __restrict__ g, const float* __restrict__ b,
    const float* __restrict__ WT1, const float* __restrict__ bias,
    float* __restrict__ u2, float* __restrict__ ffact)
{
    const int r = blockIdx.x;
    const int tid = threadIdx.x;
    const int w = tid >> 6, lane = tid & 63;
    __shared__ float su[DD];
    __shared__ float red[16];

    float v0 = u2pre[r * DD + tid], v1 = u2pre[r * DD + 256 + tid];
    float s1 = v0 + v1, s2 = v0 * v0 + v1 * v1;
    #pragma unroll
    for (int off = 32; off; off >>= 1) { s1 += __shfl_xor(s1, off); s2 += __shfl_xor(s2, off); }
    if (lane == 0) { red[w] = s1; red[8 + w] = s2; }
    __syncthreads();
    float sum = red[0] + red[1] + red[2] + red[3];
    float sq  = red[8] + red[9] + red[10] + red[11];
    float mean = sum * (1.f / 512.f);
    float var  = sq * (1.f / 512.f) - mean * mean;
    float rstd = rsqrtf(var + 1e-5f);
    float a0 = fmaf((v0 - mean) * rstd, g[tid], b[tid]);
    float a1 = fmaf((v1 - mean) * rstd, g[tid + 256], b[tid + 256]);
    su[tid] = a0; su[tid + 256] = a1;
    u2[r * DD + tid] = a0; u2[r * DD + 256 + tid] = a1;
    __syncthreads();

    float f[8];
    #pragma unroll
    for (int c = 0; c < 8; ++c) f[c] = 0.f;
    #pragma unroll 4
    for (int k = 0; k < DD; ++k) {
        float xv = su[k];
        const float* wr = &WT1[(long)k * DFF + tid];
        #pragma unroll
        for (int c = 0; c < 8; ++c)
            f[c] = fmaf(xv, wr[c * 256], f[c]);
    }
    #pragma unroll
    for (int c = 0; c < 8; ++c)
        ffact[r * DFF + c * 256 + tid] = fmaxf(f[c] + bias[c * 256 + tid], 0.f);
}

// S8: ff2 split-K=4 partials. 128 blocks x 256; pbuf[ks][64][512].
__global__ __launch_bounds__(256) void dff2_k(
    const float* __restrict__ ffact,   // [64][2048]
    const float* __restrict__ WT2,     // [2048][512]
    float* __restrict__ pbuf)
{
    const int gid = blockIdx.x * 256 + threadIdx.x;  // 0..32767
    const int ks  = gid >> 13;
    const int qid = gid & 8191;
    const int r = qid >> 7;
    const int col0 = (qid & 127) * 4;
    const float* xr = &ffact[r * DFF + ks * 512];
    const float* wp = &WT2[(long)(ks * 512) * DD];
    float4 acc = make_float4(0.f, 0.f, 0.f, 0.f);
    #pragma unroll 8
    for (int k = 0; k < 512; ++k) {
        float xv = xr[k];
        float4 w = *(const float4*)&wp[(long)k * DD + col0];
        acc.x = fmaf(xv, w.x, acc.x); acc.y = fmaf(xv, w.y, acc.y);
        acc.z = fmaf(xv, w.z, acc.z); acc.w = fmaf(xv, w.w, acc.w);
    }
    *(float4*)&pbuf[((long)ks * BB + r) * DD + col0] = acc;
}

// S9: sum partials + bias + residual(u2), LN(g3,b3), final LN(gn,bn) -> tgt.
__global__ __launch_bounds__(256) void dln2x_k(
    const float* __restrict__ pbuf, const float* __restrict__ bias,
    const float* __restrict__ u2,
    const float* __restrict__ g3, const float* __restrict__ b3,
    const float* __restrict__ gn, const float* __restrict__ bn,
    float* __restrict__ tgt, int t)
{
    const int r = blockIdx.x;
    const int tid = threadIdx.x;
    const int w = tid >> 6, lane = tid & 63;
    __shared__ float red[16];

    float v0 = bias[tid] + u2[r * DD + tid];
    float v1 = bias[tid + 256] + u2[r * DD + 256 + tid];
    #pragma unroll
    for (int ks = 0; ks < 4; ++ks) {
        v0 += pbuf[((long)ks * BB + r) * DD + tid];
        v1 += pbuf[((long)ks * BB + r) * DD + 256 + tid];
    }

    // LN(g3,b3)
    float s1 = v0 + v1, s2 = v0 * v0 + v1 * v1;
    #pragma unroll
    for (int off = 32; off; off >>= 1) { s1 += __shfl_xor(s1, off); s2 += __shfl_xor(s2, off); }
    if (lane == 0) { red[w] = s1; red[8 + w] = s2; }
    __syncthreads();
    float sum = red[0] + red[1] + red[2] + red[3];
    float sq  = red[8] + red[9] + red[10] + red[11];
    float mean = sum * (1.f / 512.f);
    float var  = sq * (1.f / 512.f) - mean * mean;
    float rstd = rsqrtf(var + 1e-5f);
    float y0 = fmaf((v0 - mean) * rstd, g3[tid], b3[tid]);
    float y1 = fmaf((v1 - mean) * rstd, g3[tid + 256], b3[tid + 256]);

    // final LN(gn,bn)
    __syncthreads();
    s1 = y0 + y1; s2 = y0 * y0 + y1 * y1;
    #pragma unroll
    for (int off = 32; off; off >>= 1) { s1 += __shfl_xor(s1, off); s2 += __shfl_xor(s2, off); }
    if (lane == 0) { red[w] = s1; red[8 + w] = s2; }
    __syncthreads();
    sum = red[0] + red[1] + red[2] + red[3];
    sq  = red[8] + red[9] + red[10] + red[11];
    mean = sum * (1.f / 512.f);
    var  = sq * (1.f / 512.f) - mean * mean;
    rstd = rsqrtf(var + 1e-5f);
    float* O = &tgt[((long)r * TCAP + t + 1) * DD];
    O[tid]       = fmaf((y0 - mean) * rstd, gn[tid], bn[tid]);
    O[tid + 256] = fmaf((y1 - mean) * rstd, gn[tid + 256], bn[tid + 256]);
}

// tgt[:,0,:] = start_token
__global__ __launch_bounds__(256) void init_tgt_k(
    const float* __restrict__ start, float* __restrict__ tgt)
{
    int idx = blockIdx.x * 256 + threadIdx.x;
    if (idx >= BB * DD) return;
    int b = idx >> 9, d = idx & 511;
    tgt[(long)b * TCAP * DD + d] = start[d];
}

// packed[b*16+s][d] = tgt[b][s+1][d]
__global__ __launch_bounds__(256) void pack_k(
    const float* __restrict__ tgt, float* __restrict__ packed)
{
    int idx = blockIdx.x * 256 + threadIdx.x;
    if (idx >= BB * TLEN * DD) return;
    int d = idx & 511;
    int r = idx >> 9;
    int b = r >> 4, s = r & 15;
    packed[idx] = tgt[((long)b * TCAP + s + 1) * DD + d];
}

// ---------------------------------------------------------------------------
extern "C" void kernel_launch(void* const* d_in, const int* in_sizes, int n_in,
                              void* d_out, int out_size, void* d_ws, size_t ws_size,
                              hipStream_t stream) {
    const float* x          = (const float*)d_in[0];
    const float* W_in       = (const float*)d_in[1];
    const float* b_in       = (const float*)d_in[2];
    const float* start_tok  = (const float*)d_in[3];
    const float* enc_qkv_w  = (const float*)d_in[4];
    const float* enc_qkv_b  = (const float*)d_in[5];
    const float* enc_out_w  = (const float*)d_in[6];
    const float* enc_out_b  = (const float*)d_in[7];
    const float* enc_ln1_g  = (const float*)d_in[8];
    const float* enc_ln1_b  = (const float*)d_in[9];
    const float* enc_ff1_w  = (const float*)d_in[10];
    const float* enc_ff1_b  = (const float*)d_in[11];
    const float* enc_ff2_w  = (const float*)d_in[12];
    const float* enc_ff2_b  = (const float*)d_in[13];
    const float* enc_ln2_g  = (const float*)d_in[14];
    const float* enc_ln2_b  = (const float*)d_in[15];
    const float* enc_norm_g = (const float*)d_in[16];
    const float* enc_norm_b = (const float*)d_in[17];
    const float* dsa_qkv_w  = (const float*)d_in[18];
    const float* dsa_qkv_b  = (const float*)d_in[19];
    const float* dsa_out_w  = (const float*)d_in[20];
    const float* dsa_out_b  = (const float*)d_in[21];
    const float* dln1_g     = (const float*)d_in[22];
    const float* dln1_b     = (const float*)d_in[23];
    const float* dca_qkv_w  = (const float*)d_in[24];
    const float* dca_qkv_b  = (const float*)d_in[25];
    const float* dca_out_w  = (const float*)d_in[26];
    const float* dca_out_b  = (const float*)d_in[27];
    const float* dln2_g     = (const float*)d_in[28];
    const float* dln2_b     = (const float*)d_in[29];
    const float* dff1_w     = (const float*)d_in[30];
    const float* dff1_b     = (const float*)d_in[31];
    const float* dff2_w     = (const float*)d_in[32];
    const float* dff2_b     = (const float*)d_in[33];
    const float* dln3_g     = (const float*)d_in[34];
    const float* dln3_b     = (const float*)d_in[35];
    const float* dnorm_g    = (const float*)d_in[36];
    const float* dnorm_b    = (const float*)d_in[37];
    const float* W_out      = (const float*)d_in[38];
    const float* b_out      = (const float*)d_in[39];
    // d_in[40] = description_length (fixed 16; hardcoded)

    float* ws = (float*)d_ws;
    const size_t A = AREG;
    float* buf0 = ws;                 // src -> mem
    float* buf1 = ws + 1 * A;         // q   -> tmp -> tmp2
    float* buf2 = ws + 2 * A;         // k   -> h1  -> memK
    float* buf3 = ws + 3 * A;         // v   -> ff(lo)-> memV
    float* buf4 = ws + 4 * A;         // attn-> ff(hi)
    float* src  = buf0;
    float* qh   = buf1;
    float* attn = buf4;
    float* tmp  = buf1;
    float* h1   = buf2;
    float* ffbuf= buf3;               // [8192, 2048] = 2A (buf3..buf4)
    float* tmp2 = buf1;
    float* mem  = buf0;
    float* memK = buf2;               // memV at buf3 (mode-2 which*A)

    float* sb     = ws + 5 * A;
    float* tgt    = sb;                      // BB*TCAP*DD = 557056
    float* kcache = tgt + BH17;              // 557056
    float* vcache = kcache + BH17;           // 557056
    float* qbuf   = vcache + BH17;           // 32768
    float* sao    = qbuf + 32768;
    float* upre   = sao + 32768;
    float* u      = upre + 32768;
    float* caq    = u + 32768;
    float* cao    = caq + 32768;
    float* u2pre  = cao + 32768;
    float* u2     = u2pre + 32768;
    float* ffact  = u2 + 32768;              // 131072
    float* pbuf   = ffact + 131072;          // 131072
    float* packed = pbuf + 131072;           // 524288
    // pre-transposed decode weights (WT[K][N])
    float* wt_qkv = packed + 524288;         // 512 x 1536
    float* wt_sao = wt_qkv + 786432;         // 512 x 512
    float* wt_caq = wt_sao + 262144;
    float* wt_cao = wt_caq + 262144;
    float* wt_ff1 = wt_cao + 262144;         // 512 x 2048
    float* wt_ff2 = wt_ff1 + 1048576;        // 2048 x 512

    auto gemm = [&](const float* Ap, int lda, const float* Wp, const float* bp,
                    float* outp, int M, int N, int K, int mode) {
        dim3 g((M + BM - 1) / BM, N / BN);
        gemm_k<<<g, 256, 0, stream>>>(Ap, lda, Wp, bp, outp, M, N, K, mode);
    };
    auto ln = [&](const float* xp, const float* rp,
                  const float* g1, const float* b1, const float* g2, const float* b2,
                  float* op, int nrows, int dbl) {
        ln_k<<<(nrows + 3) / 4, 256, 0, stream>>>(xp, rp, g1, b1, g2, b2, op, nrows, dbl);
    };
    auto tr = [&](const float* Wp, float* WTp, int N, int K) {
        tr_k<<<dim3(N / 32, K / 32), 256, 0, stream>>>(Wp, WTp, N, K);
    };

    const int MS = BB * SS;  // 16384

    // ---- One-time decode weight transposes ----
    tr(dsa_qkv_w, wt_qkv, 3 * DD, DD);
    tr(dsa_out_w, wt_sao, DD, DD);
    tr(dca_qkv_w, wt_caq, DD, DD);     // q-part = first 512 rows
    tr(dca_out_w, wt_cao, DD, DD);
    tr(dff1_w,    wt_ff1, DFF, DD);
    tr(dff2_w,    wt_ff2, DD, DFF);

    // ---- Encoder ----
    gemm(x, DIN, W_in, b_in, src, MS, DD, DIN, 0);
    gemm(src, DD, enc_qkv_w, enc_qkv_b, qh, MS, 3 * DD, DD, 2);
    enc_attn_k<<<BB * NH, 256, 0, stream>>>(buf1, buf2, buf3, attn);
    gemm(attn, DD, enc_out_w, enc_out_b, tmp, MS, DD, DD, 0);
    ln(tmp, src, enc_ln1_g, enc_ln1_b, nullptr, nullptr, h1, MS, 0);
    for (int c = 0; c < 2; ++c) {
        int roff = c * (MS / 2);
        gemm(h1 + (long)roff * DD, DD, enc_ff1_w, enc_ff1_b, ffbuf, MS / 2, DFF, DD, 1);
        gemm(ffbuf, DFF, enc_ff2_w, enc_ff2_b, tmp2 + (long)roff * DD, MS / 2, DD, DFF, 0);
    }
    ln(tmp2, h1, enc_ln2_g, enc_ln2_b, enc_norm_g, enc_norm_b, mem, MS, 1);
    gemm(mem, DD, dca_qkv_w + 512 * 512, dca_qkv_b + 512, memK, MS, 2 * DD, DD, 2);

    // ---- Decoder: column-parallel stages ----
    init_tgt_k<<<(BB * DD + 255) / 256, 256, 0, stream>>>(start_tok, tgt);

    for (int t = 0; t < TLEN; ++t) {
        dqkv_k<<<96, 256, 0, stream>>>(tgt, wt_qkv, dsa_qkv_b, qbuf, kcache, vcache, t);
        dec_sa_k<<<BB * NH, 64, 0, stream>>>(qbuf, kcache, vcache, sao, t);
        dproj_k<<<32, 256, 0, stream>>>(sao, wt_sao, dsa_out_b,
                                        tgt + (long)t * DD, (long)TCAP * DD, upre);
        dlnproj_k<<<BB, 256, 0, stream>>>(upre, dln1_g, dln1_b, wt_caq, dca_qkv_b, u, caq);
        dec_ca_k<<<BB * NH, 256, 0, stream>>>(caq, memK, memK + A, cao);
        dproj_k<<<32, 256, 0, stream>>>(cao, wt_cao, dca_out_b, u, DD, u2pre);
        dlnff1_k<<<BB, 256, 0, stream>>>(u2pre, dln2_g, dln2_b, wt_ff1, dff1_b, u2, ffact);
        dff2_k<<<128, 256, 0, stream>>>(ffact, wt_ff2, pbuf);
        dln2x_k<<<BB, 256, 0, stream>>>(pbuf, dff2_b, u2, dln3_g, dln3_b,
                                        dnorm_g, dnorm_b, tgt, t);
    }

    // ---- Output projection ----
    pack_k<<<(BB * TLEN * DD + 255) / 256, 256, 0, stream>>>(tgt, packed);
    gemm(packed, DD, W_out, b_out, (float*)d_out, BB * TLEN, DD, DD, 0);
}

// Round 8
// 5592.696 us; speedup vs baseline: 2.2470x; 1.0254x over previous
//
#include <hip/hip_runtime.h>
#include <hip/hip_bf16.h>

// Problem constants
#define BB   64
#define SS   256
#define DD   512
#define DFF  2048
#define DIN  256
#define NH   8
#define DH   64
#define TLEN 16
#define TCAP 17

constexpr size_t AREG = (size_t)BB * SS * DD;   // 8,388,608 floats
constexpr int    BH17 = BB * NH * TCAP * DH;    // 557,056

typedef __attribute__((ext_vector_type(8))) short bf16x8;   // 8 bf16 (4 VGPRs)
typedef __attribute__((ext_vector_type(4))) float f32x4;    // MFMA acc

// split fp32 -> hi (truncated bf16) + lo (bf16 of residual); a ~= hi + lo
__device__ __forceinline__ void f2bf2(float x, short& hi, short& lo) {
    unsigned xb = __float_as_uint(x);
    unsigned hb = xb & 0xffff0000u;
    float r = x - __uint_as_float(hb);   // exact
    hi = (short)(hb >> 16);
    lo = (short)(__float_as_uint(r) >> 16);
}

// ---------------------------------------------------------------------------
// Weight split kernel: W fp32 [n] -> hi/lo bf16 bits
// ---------------------------------------------------------------------------
__global__ __launch_bounds__(256) void wconv_k(
    const float* __restrict__ W, short* __restrict__ hi,
    short* __restrict__ lo, int n4)
{
    int i = blockIdx.x * 256 + threadIdx.x;
    if (i >= n4) return;
    float4 v = *(const float4*)&W[(long)i * 4];
    short h0,h1,h2,h3,l0,l1,l2,l3;
    f2bf2(v.x,h0,l0); f2bf2(v.y,h1,l1); f2bf2(v.z,h2,l2); f2bf2(v.w,h3,l3);
    *(short4*)&hi[(long)i * 4] = make_short4(h0,h1,h2,h3);
    *(short4*)&lo[(long)i * 4] = make_short4(l0,l1,l2,l3);
}

// ---------------------------------------------------------------------------
// Split-bf16 MFMA GEMM: C[M,N] = A[M,K] @ W[N,K]^T + bias (fp32-comparable
// accuracy via 3 MFMAs: hi*hi + hi*lo + lo*hi; fp32 accumulate).
// 128x128x32 tile, 256 thr = 4 waves (2x2 of 64x64), mfma_f32_16x16x32_bf16.
// A: fp32 global, converted during staging. W: pre-split hi/lo bf16.
// mode 0 plain, 1 relu, 2 qkv head-scatter.
// M mult of 128 guarded; N mult of 128; K mult of 32.
// ---------------------------------------------------------------------------
#define MPAD 40   // shorts per LDS row (32 + 8 pad: breaks pow2 bank stride)

__global__ __launch_bounds__(256) void mgemm_k(
    const float* __restrict__ A, int lda,
    const short* __restrict__ Whi, const short* __restrict__ Wlo,
    const float* __restrict__ bias,
    float* __restrict__ out,
    int M, int N, int K, int mode)
{
    __shared__ short sAh[128][MPAD], sAl[128][MPAD];
    __shared__ short sBh[128][MPAD], sBl[128][MPAD];

    const int row0 = blockIdx.x * 128, col0 = blockIdx.y * 128;
    const int tid  = threadIdx.x;
    const int wave = tid >> 6, lane = tid & 63;
    const int wm = wave >> 1, wn = wave & 1;
    const int l15 = lane & 15, l4 = lane >> 4;

    f32x4 acc[4][4];
    #pragma unroll
    for (int i = 0; i < 4; ++i)
        #pragma unroll
        for (int j = 0; j < 4; ++j) acc[i][j] = (f32x4){0.f, 0.f, 0.f, 0.f};

    const int srow = tid >> 1;          // 0..127
    const int sks  = (tid & 1) * 16;    // 0 or 16
    const int grow = row0 + srow;
    const int gcol = col0 + srow;

    for (int k0 = 0; k0 < K; k0 += 32) {
        // stage A tile with on-the-fly split
        {
            short h[16], l[16];
            if (grow < M) {
                const float* ap = &A[(long)grow * lda + k0 + sks];
                #pragma unroll
                for (int i = 0; i < 4; ++i) {
                    float4 v = *(const float4*)&ap[i * 4];
                    f2bf2(v.x, h[i*4+0], l[i*4+0]);
                    f2bf2(v.y, h[i*4+1], l[i*4+1]);
                    f2bf2(v.z, h[i*4+2], l[i*4+2]);
                    f2bf2(v.w, h[i*4+3], l[i*4+3]);
                }
            } else {
                #pragma unroll
                for (int i = 0; i < 16; ++i) { h[i] = 0; l[i] = 0; }
            }
            *(bf16x8*)&sAh[srow][sks]     = *(bf16x8*)&h[0];
            *(bf16x8*)&sAh[srow][sks + 8] = *(bf16x8*)&h[8];
            *(bf16x8*)&sAl[srow][sks]     = *(bf16x8*)&l[0];
            *(bf16x8*)&sAl[srow][sks + 8] = *(bf16x8*)&l[8];
        }
        // stage B tile (already split)
        {
            const short* wh = &Whi[(long)gcol * K + k0 + sks];
            const short* wl = &Wlo[(long)gcol * K + k0 + sks];
            *(bf16x8*)&sBh[srow][sks]     = *(const bf16x8*)&wh[0];
            *(bf16x8*)&sBh[srow][sks + 8] = *(const bf16x8*)&wh[8];
            *(bf16x8*)&sBl[srow][sks]     = *(const bf16x8*)&wl[0];
            *(bf16x8*)&sBl[srow][sks + 8] = *(const bf16x8*)&wl[8];
        }
        __syncthreads();

        // fragments: A row = lane&15, k = (lane>>4)*8 + reg (contig 8)
        bf16x8 ah[4], al[4], bh[4], bl[4];
        #pragma unroll
        for (int i = 0; i < 4; ++i) {
            ah[i] = *(const bf16x8*)&sAh[wm * 64 + i * 16 + l15][l4 * 8];
            al[i] = *(const bf16x8*)&sAl[wm * 64 + i * 16 + l15][l4 * 8];
            bh[i] = *(const bf16x8*)&sBh[wn * 64 + i * 16 + l15][l4 * 8];
            bl[i] = *(const bf16x8*)&sBl[wn * 64 + i * 16 + l15][l4 * 8];
        }
        #pragma unroll
        for (int mi = 0; mi < 4; ++mi)
            #pragma unroll
            for (int ni = 0; ni < 4; ++ni) {
                acc[mi][ni] = __builtin_amdgcn_mfma_f32_16x16x32_bf16(ah[mi], bh[ni], acc[mi][ni], 0, 0, 0);
                acc[mi][ni] = __builtin_amdgcn_mfma_f32_16x16x32_bf16(ah[mi], bl[ni], acc[mi][ni], 0, 0, 0);
                acc[mi][ni] = __builtin_amdgcn_mfma_f32_16x16x32_bf16(al[mi], bh[ni], acc[mi][ni], 0, 0, 0);
            }
        __syncthreads();
    }

    // epilogue: C/D layout col = lane&15, row = (lane>>4)*4 + reg
    #pragma unroll
    for (int ni = 0; ni < 4; ++ni) {
        const int gc = col0 + wn * 64 + ni * 16 + l15;
        const float bv = bias[gc];
        #pragma unroll
        for (int mi = 0; mi < 4; ++mi) {
            #pragma unroll
            for (int j = 0; j < 4; ++j) {
                int gr = row0 + wm * 64 + mi * 16 + l4 * 4 + j;
                if (gr >= M) continue;
                float o = acc[mi][ni][j] + bv;
                if (mode == 1) o = fmaxf(o, 0.f);
                if (mode <= 1) {
                    out[(long)gr * N + gc] = o;
                } else {
                    int b = gr >> 8, s = gr & 255;
                    int which = gc >> 9, h = (gc >> 6) & 7, d = gc & 63;
                    out[(long)which * AREG + (((b * 8 + h) * 256 + s) * 64 + d)] = o;
                }
            }
        }
    }
}

// ---------------------------------------------------------------------------
// Encoder fused attention (unchanged)
// ---------------------------------------------------------------------------
__global__ __launch_bounds__(256) void enc_attn_k(
    const float* __restrict__ q, const float* __restrict__ k,
    const float* __restrict__ v, float* __restrict__ out)
{
    const int bh = blockIdx.x;
    const int b = bh >> 3, h = bh & 7;
    const float* Q = q + (long)bh * SS * DH;
    const float* Kp = k + (long)bh * SS * DH;
    const float* Vp = v + (long)bh * SS * DH;
    const int t = threadIdx.x;

    __shared__ float4 sK[16][16];
    __shared__ float4 sV[16][16];

    float4 q4[16];
    #pragma unroll
    for (int i = 0; i < 16; ++i) q4[i] = *(const float4*)&Q[t * 64 + i * 4];

    float4 o4[16];
    #pragma unroll
    for (int i = 0; i < 16; ++i) o4[i] = make_float4(0.f, 0.f, 0.f, 0.f);
    float m = -1e30f, l = 0.f;

    const int r = t >> 4, c4 = t & 15;
    for (int c = 0; c < 16; ++c) {
        sK[r][c4] = *(const float4*)&Kp[(c * 16 + r) * 64 + c4 * 4];
        sV[r][c4] = *(const float4*)&Vp[(c * 16 + r) * 64 + c4 * 4];
        __syncthreads();

        float sc[16];
        #pragma unroll
        for (int kk = 0; kk < 16; ++kk) {
            float s = 0.f;
            #pragma unroll
            for (int i = 0; i < 16; ++i) {
                float4 kv = sK[kk][i];
                s = fmaf(q4[i].x, kv.x, s); s = fmaf(q4[i].y, kv.y, s);
                s = fmaf(q4[i].z, kv.z, s); s = fmaf(q4[i].w, kv.w, s);
            }
            sc[kk] = s * 0.125f;
        }
        float cm = sc[0];
        #pragma unroll
        for (int kk = 1; kk < 16; ++kk) cm = fmaxf(cm, sc[kk]);
        float mn = fmaxf(m, cm);
        float alpha = __expf(m - mn);
        float ps[16]; float psum = 0.f;
        #pragma unroll
        for (int kk = 0; kk < 16; ++kk) { ps[kk] = __expf(sc[kk] - mn); psum += ps[kk]; }
        l = l * alpha + psum;
        #pragma unroll
        for (int i = 0; i < 16; ++i) {
            o4[i].x *= alpha; o4[i].y *= alpha; o4[i].z *= alpha; o4[i].w *= alpha;
        }
        #pragma unroll
        for (int kk = 0; kk < 16; ++kk) {
            float p = ps[kk];
            #pragma unroll
            for (int i = 0; i < 16; ++i) {
                float4 vv = sV[kk][i];
                o4[i].x = fmaf(p, vv.x, o4[i].x); o4[i].y = fmaf(p, vv.y, o4[i].y);
                o4[i].z = fmaf(p, vv.z, o4[i].z); o4[i].w = fmaf(p, vv.w, o4[i].w);
            }
        }
        m = mn;
        __syncthreads();
    }

    float inv = 1.f / l;
    float* O = out + ((long)(b * SS + t)) * DD + h * DH;
    #pragma unroll
    for (int i = 0; i < 16; ++i) {
        float4 v_;
        v_.x = o4[i].x * inv; v_.y = o4[i].y * inv;
        v_.z = o4[i].z * inv; v_.w = o4[i].w * inv;
        *(float4*)&O[i * 4] = v_;
    }
}

// ---------------------------------------------------------------------------
// Encoder LayerNorm (unchanged): out = LN(x + r); dbl=1: LN2(LN1(x+r)).
// ---------------------------------------------------------------------------
__global__ __launch_bounds__(256) void ln_k(
    const float* __restrict__ x,
    const float* __restrict__ r,
    const float* __restrict__ g1, const float* __restrict__ b1,
    const float* __restrict__ g2, const float* __restrict__ b2,
    float* __restrict__ out, int nrows, int dbl)
{
    const int row = blockIdx.x * 4 + (threadIdx.x >> 6);
    if (row >= nrows) return;
    const int lane = threadIdx.x & 63;

    const float* X = x + (long)row * DD;
    const float* R = r + (long)row * DD;
    float y[8];
    {
        float4 a = *(const float4*)&X[lane * 4];
        float4 c = *(const float4*)&X[256 + lane * 4];
        float4 ra = *(const float4*)&R[lane * 4];
        float4 rc = *(const float4*)&R[256 + lane * 4];
        y[0] = a.x + ra.x; y[1] = a.y + ra.y; y[2] = a.z + ra.z; y[3] = a.w + ra.w;
        y[4] = c.x + rc.x; y[5] = c.y + rc.y; y[6] = c.z + rc.z; y[7] = c.w + rc.w;
    }
    float sum = 0.f, sq = 0.f;
    #pragma unroll
    for (int i = 0; i < 8; ++i) { sum += y[i]; sq = fmaf(y[i], y[i], sq); }
    #pragma unroll
    for (int off = 32; off; off >>= 1) {
        sum += __shfl_xor(sum, off);
        sq  += __shfl_xor(sq, off);
    }
    float mean = sum * (1.f / 512.f);
    float var  = sq * (1.f / 512.f) - mean * mean;
    float rstd = rsqrtf(var + 1e-5f);
    {
        float4 ga = *(const float4*)&g1[lane * 4];
        float4 gc = *(const float4*)&g1[256 + lane * 4];
        float4 ba = *(const float4*)&b1[lane * 4];
        float4 bc = *(const float4*)&b1[256 + lane * 4];
        float gs[8] = {ga.x, ga.y, ga.z, ga.w, gc.x, gc.y, gc.z, gc.w};
        float bs[8] = {ba.x, ba.y, ba.z, ba.w, bc.x, bc.y, bc.z, bc.w};
        #pragma unroll
        for (int i = 0; i < 8; ++i) y[i] = fmaf((y[i] - mean) * rstd, gs[i], bs[i]);
    }
    if (dbl) {
        float sum2 = 0.f, sq2 = 0.f;
        #pragma unroll
        for (int i = 0; i < 8; ++i) { sum2 += y[i]; sq2 = fmaf(y[i], y[i], sq2); }
        #pragma unroll
        for (int off = 32; off; off >>= 1) {
            sum2 += __shfl_xor(sum2, off);
            sq2  += __shfl_xor(sq2, off);
        }
        float mean2 = sum2 * (1.f / 512.f);
        float var2  = sq2 * (1.f / 512.f) - mean2 * mean2;
        float rstd2 = rsqrtf(var2 + 1e-5f);
        float4 ga = *(const float4*)&g2[lane * 4];
        float4 gc = *(const float4*)&g2[256 + lane * 4];
        float4 ba = *(const float4*)&b2[lane * 4];
        float4 bc = *(const float4*)&b2[256 + lane * 4];
        float gs[8] = {ga.x, ga.y, ga.z, ga.w, gc.x, gc.y, gc.z, gc.w};
        float bs[8] = {ba.x, ba.y, ba.z, ba.w, bc.x, bc.y, bc.z, bc.w};
        #pragma unroll
        for (int i = 0; i < 8; ++i) y[i] = fmaf((y[i] - mean2) * rstd2, gs[i], bs[i]);
    }
    float* O = out + (long)row * DD;
    *(float4*)&O[lane * 4] = make_float4(y[0], y[1], y[2], y[3]);
    *(float4*)&O[256 + lane * 4] = make_float4(y[4], y[5], y[6], y[7]);
}

// ===========================================================================
// DECODE — weight-broadcast matmul. Wave = 64 batch rows (lanes), 4 cols per
// wave, original W[N][K] layout: all 64 lanes read the SAME weight address
// (hardware broadcast) -> per-block weight traffic = 16 cols x K x 4B only.
// (round-6 lesson: per-block multi-MB weight streams are per-CU L2-BW-bound)
// ===========================================================================
__global__ __launch_bounds__(256) void dmm_k(
    const float* __restrict__ x, long xs,    // [64][K], row stride xs
    const float* __restrict__ W,             // [N][K] fp32
    const float* __restrict__ bias,
    const float* __restrict__ res, long rs,  // optional residual
    float* __restrict__ out,
    float* __restrict__ kc, float* __restrict__ vc, int t,  // mode 2
    int N, int K, int mode)                  // 0 plain, 1 relu, 2 qkv scatter
{
    __shared__ float sx[64][68];             // 68 = 64 + 4: conflict-free pad
    const int tid  = threadIdx.x;
    const int wave = tid >> 6, lane = tid & 63;
    const int colbase = blockIdx.x * 16 + wave * 4;

    const float* w0 = &W[(long)(colbase + 0) * K];
    const float* w1 = &W[(long)(colbase + 1) * K];
    const float* w2 = &W[(long)(colbase + 2) * K];
    const float* w3 = &W[(long)(colbase + 3) * K];

    float acc0 = 0.f, acc1 = 0.f, acc2 = 0.f, acc3 = 0.f;

    for (int kb = 0; kb < K; kb += 64) {
        // stage x[:, kb..kb+63] (coalesced)
        {
            int r  = tid >> 2;
            int c0 = (tid & 3) * 16;
            #pragma unroll
            for (int i = 0; i < 4; ++i) {
                float4 v = *(const float4*)&x[(long)r * xs + kb + c0 + i * 4];
                *(float4*)&sx[r][c0 + i * 4] = v;
            }
        }
        __syncthreads();
        #pragma unroll 4
        for (int k = 0; k < 64; k += 4) {
            float4 xv = *(const float4*)&sx[lane][k];     // own row
            float4 a4 = *(const float4*)&w0[kb + k];      // broadcast
            acc0 = fmaf(xv.x, a4.x, acc0); acc0 = fmaf(xv.y, a4.y, acc0);
            acc0 = fmaf(xv.z, a4.z, acc0); acc0 = fmaf(xv.w, a4.w, acc0);
            float4 b4 = *(const float4*)&w1[kb + k];
            acc1 = fmaf(xv.x, b4.x, acc1); acc1 = fmaf(xv.y, b4.y, acc1);
            acc1 = fmaf(xv.z, b4.z, acc1); acc1 = fmaf(xv.w, b4.w, acc1);
            float4 c4 = *(const float4*)&w2[kb + k];
            acc2 = fmaf(xv.x, c4.x, acc2); acc2 = fmaf(xv.y, c4.y, acc2);
            acc2 = fmaf(xv.z, c4.z, acc2); acc2 = fmaf(xv.w, c4.w, acc2);
            float4 d4 = *(const float4*)&w3[kb + k];
            acc3 = fmaf(xv.x, d4.x, acc3); acc3 = fmaf(xv.y, d4.y, acc3);
            acc3 = fmaf(xv.z, d4.z, acc3); acc3 = fmaf(xv.w, d4.w, acc3);
        }
        __syncthreads();
    }

    float accs[4] = {acc0, acc1, acc2, acc3};
    #pragma unroll
    for (int c = 0; c < 4; ++c) {
        int col = colbase + c;
        float o = accs[c] + bias[col];
        if (mode == 1) o = fmaxf(o, 0.f);
        if (res) o += res[(long)lane * rs + col];
        if (mode == 2) {
            int which = col >> 9, cc = col & 511;
            int h = cc >> 6, d = cc & 63;
            if (which == 0) out[lane * DD + cc] = o;
            else ((which == 1) ? kc : vc)[(((long)lane * NH + h) * TCAP + t) * DH + d] = o;
        } else {
            out[(long)lane * N + col] = o;
        }
    }
}

// Decode LN (no residual; optionally double LN). 64 rows, 16 blocks x 4 rows.
__global__ __launch_bounds__(256) void dln_k(
    const float* __restrict__ x, long xsr,
    const float* __restrict__ g1, const float* __restrict__ b1,
    const float* __restrict__ g2, const float* __restrict__ b2,
    float* __restrict__ out, long osr, int dbl)
{
    const int row = blockIdx.x * 4 + (threadIdx.x >> 6);
    const int lane = threadIdx.x & 63;
    const float* X = x + (long)row * xsr;
    float y[8];
    {
        float4 a = *(const float4*)&X[lane * 4];
        float4 c = *(const float4*)&X[256 + lane * 4];
        y[0] = a.x; y[1] = a.y; y[2] = a.z; y[3] = a.w;
        y[4] = c.x; y[5] = c.y; y[6] = c.z; y[7] = c.w;
    }
    float sum = 0.f, sq = 0.f;
    #pragma unroll
    for (int i = 0; i < 8; ++i) { sum += y[i]; sq = fmaf(y[i], y[i], sq); }
    #pragma unroll
    for (int off = 32; off; off >>= 1) {
        sum += __shfl_xor(sum, off); sq += __shfl_xor(sq, off);
    }
    float mean = sum * (1.f / 512.f);
    float var  = sq * (1.f / 512.f) - mean * mean;
    float rstd = rsqrtf(var + 1e-5f);
    #pragma unroll
    for (int i = 0; i < 8; ++i) {
        int idx = (i < 4) ? lane * 4 + i : 256 + lane * 4 + (i - 4);
        y[i] = fmaf((y[i] - mean) * rstd, g1[idx], b1[idx]);
    }
    if (dbl) {
        float s2 = 0.f, q2 = 0.f;
        #pragma unroll
        for (int i = 0; i < 8; ++i) { s2 += y[i]; q2 = fmaf(y[i], y[i], q2); }
        #pragma unroll
        for (int off = 32; off; off >>= 1) {
            s2 += __shfl_xor(s2, off); q2 += __shfl_xor(q2, off);
        }
        float mean2 = s2 * (1.f / 512.f);
        float var2  = q2 * (1.f / 512.f) - mean2 * mean2;
        float rstd2 = rsqrtf(var2 + 1e-5f);
        #pragma unroll
        for (int i = 0; i < 8; ++i) {
            int idx = (i < 4) ? lane * 4 + i : 256 + lane * 4 + (i - 4);
            y[i] = fmaf((y[i] - mean2) * rstd2, g2[idx], b2[idx]);
        }
    }
    float* O = out + (long)row * osr;
    *(float4*)&O[lane * 4] = make_float4(y[0], y[1], y[2], y[3]);
    *(float4*)&O[256 + lane * 4] = make_float4(y[4], y[5], y[6], y[7]);
}

// Decode self-attention with KV cache (unchanged).
__global__ __launch_bounds__(64) void dec_sa_k(
    const float* __restrict__ qbuf, const float* __restrict__ kc,
    const float* __restrict__ vc, float* __restrict__ out, int t)
{
    const int bh = blockIdx.x;
    const int b = bh >> 3, h = bh & 7;
    const int lane = threadIdx.x;
    const int L = t + 1;

    __shared__ float sq[64];
    __shared__ float sp[64];

    sq[lane] = qbuf[b * DD + h * DH + lane];
    __syncthreads();

    const float* K = kc + (long)bh * TCAP * DH;
    float s = -1e30f;
    if (lane < L) {
        float acc = 0.f;
        #pragma unroll
        for (int d = 0; d < 64; d += 4) {
            float4 kr = *(const float4*)&K[lane * 64 + d];
            acc = fmaf(sq[d], kr.x, acc); acc = fmaf(sq[d + 1], kr.y, acc);
            acc = fmaf(sq[d + 2], kr.z, acc); acc = fmaf(sq[d + 3], kr.w, acc);
        }
        s = acc * 0.125f;
    }
    float mx = s;
    #pragma unroll
    for (int off = 32; off; off >>= 1) mx = fmaxf(mx, __shfl_xor(mx, off));
    float p = (lane < L) ? __expf(s - mx) : 0.f;
    float sum = p;
    #pragma unroll
    for (int off = 32; off; off >>= 1) sum += __shfl_xor(sum, off);
    sp[lane] = p;
    __syncthreads();

    const float* V = vc + (long)bh * TCAP * DH;
    float o = 0.f;
    for (int kk = 0; kk < L; ++kk) o = fmaf(sp[kk], V[kk * 64 + lane], o);
    out[b * DD + h * DH + lane] = o / sum;
}

// Decode cross-attention over mem (unchanged).
__global__ __launch_bounds__(256) void dec_ca_k(
    const float* __restrict__ caq, const float* __restrict__ mk,
    const float* __restrict__ mv, float* __restrict__ out)
{
    const int bh = blockIdx.x;
    const int b = bh >> 3, h = bh & 7;
    const int tid = threadIdx.x;

    __shared__ float sq[64];
    __shared__ float sp[256];
    __shared__ float red[8];
    __shared__ float so[4][64];

    if (tid < 64) sq[tid] = caq[b * DD + h * DH + tid];
    __syncthreads();

    const float* K = mk + (long)bh * SS * DH;
    float acc = 0.f;
    #pragma unroll
    for (int d = 0; d < 64; d += 4) {
        float4 kr = *(const float4*)&K[tid * 64 + d];
        acc = fmaf(sq[d], kr.x, acc); acc = fmaf(sq[d + 1], kr.y, acc);
        acc = fmaf(sq[d + 2], kr.z, acc); acc = fmaf(sq[d + 3], kr.w, acc);
    }
    float s = acc * 0.125f;

    float mx = s;
    #pragma unroll
    for (int off = 32; off; off >>= 1) mx = fmaxf(mx, __shfl_xor(mx, off));
    const int w = tid >> 6;
    if ((tid & 63) == 0) red[w] = mx;
    __syncthreads();
    mx = fmaxf(fmaxf(red[0], red[1]), fmaxf(red[2], red[3]));

    float p = __expf(s - mx);
    sp[tid] = p;
    float sum = p;
    #pragma unroll
    for (int off = 32; off; off >>= 1) sum += __shfl_xor(sum, off);
    if ((tid & 63) == 0) red[4 + w] = sum;
    __syncthreads();
    sum = red[4] + red[5] + red[6] + red[7];

    const float* V = mv + (long)bh * SS * DH;
    const int d = tid & 63;
    float o = 0.f;
    for (int kk = 0; kk < 64; ++kk) {
        int krow = w * 64 + kk;
        o = fmaf(sp[krow], V[krow * 64 + d], o);
    }
    so[w][d] = o;
    __syncthreads();
    if (tid < 64) {
        float rslt = (so[0][tid] + so[1][tid] + so[2][tid] + so[3][tid]) / sum;
        out[b * DD + h * DH + tid] = rslt;
    }
}

// tgt[:,0,:] = start_token
__global__ __launch_bounds__(256) void init_tgt_k(
    const float* __restrict__ start, float* __restrict__ tgt)
{
    int idx = blockIdx.x * 256 + threadIdx.x;
    if (idx >= BB * DD) return;
    int b = idx >> 9, d = idx & 511;
    tgt[(long)b * TCAP * DD + d] = start[d];
}

// packed[b*16+s][d] = tgt[b][s+1][d]
__global__ __launch_bounds__(256) void pack_k(
    const float* __restrict__ tgt, float* __restrict__ packed)
{
    int idx = blockIdx.x * 256 + threadIdx.x;
    if (idx >= BB * TLEN * DD) return;
    int d = idx & 511;
    int r = idx >> 9;
    int b = r >> 4, s = r & 15;
    packed[idx] = tgt[((long)b * TCAP + s + 1) * DD + d];
}

// ---------------------------------------------------------------------------
extern "C" void kernel_launch(void* const* d_in, const int* in_sizes, int n_in,
                              void* d_out, int out_size, void* d_ws, size_t ws_size,
                              hipStream_t stream) {
    const float* x          = (const float*)d_in[0];
    const float* W_in       = (const float*)d_in[1];
    const float* b_in       = (const float*)d_in[2];
    const float* start_tok  = (const float*)d_in[3];
    const float* enc_qkv_w  = (const float*)d_in[4];
    const float* enc_qkv_b  = (const float*)d_in[5];
    const float* enc_out_w  = (const float*)d_in[6];
    const float* enc_out_b  = (const float*)d_in[7];
    const float* enc_ln1_g  = (const float*)d_in[8];
    const float* enc_ln1_b  = (const float*)d_in[9];
    const float* enc_ff1_w  = (const float*)d_in[10];
    const float* enc_ff1_b  = (const float*)d_in[11];
    const float* enc_ff2_w  = (const float*)d_in[12];
    const float* enc_ff2_b  = (const float*)d_in[13];
    const float* enc_ln2_g  = (const float*)d_in[14];
    const float* enc_ln2_b  = (const float*)d_in[15];
    const float* enc_norm_g = (const float*)d_in[16];
    const float* enc_norm_b = (const float*)d_in[17];
    const float* dsa_qkv_w  = (const float*)d_in[18];
    const float* dsa_qkv_b  = (const float*)d_in[19];
    const float* dsa_out_w  = (const float*)d_in[20];
    const float* dsa_out_b  = (const float*)d_in[21];
    const float* dln1_g     = (const float*)d_in[22];
    const float* dln1_b     = (const float*)d_in[23];
    const float* dca_qkv_w  = (const float*)d_in[24];
    const float* dca_qkv_b  = (const float*)d_in[25];
    const float* dca_out_w  = (const float*)d_in[26];
    const float* dca_out_b  = (const float*)d_in[27];
    const float* dln2_g     = (const float*)d_in[28];
    const float* dln2_b     = (const float*)d_in[29];
    const float* dff1_w     = (const float*)d_in[30];
    const float* dff1_b     = (const float*)d_in[31];
    const float* dff2_w     = (const float*)d_in[32];
    const float* dff2_b     = (const float*)d_in[33];
    const float* dln3_g     = (const float*)d_in[34];
    const float* dln3_b     = (const float*)d_in[35];
    const float* dnorm_g    = (const float*)d_in[36];
    const float* dnorm_b    = (const float*)d_in[37];
    const float* W_out      = (const float*)d_in[38];
    const float* b_out      = (const float*)d_in[39];

    float* ws = (float*)d_ws;
    const size_t A = AREG;
    float* buf0 = ws;                 // src -> mem
    float* buf1 = ws + 1 * A;         // q   -> tmp -> tmp2
    float* buf2 = ws + 2 * A;         // k   -> h1  -> memK
    float* buf3 = ws + 3 * A;         // v   -> ff(lo) -> memV
    float* buf4 = ws + 4 * A;         // attn -> ff(hi) -> decode smalls
    float* src  = buf0;
    float* qh   = buf1;
    float* attn = buf4;
    float* tmp  = buf1;
    float* h1   = buf2;
    float* ffbuf= buf3;               // 2A (buf3..buf4)
    float* tmp2 = buf1;
    float* mem  = buf0;
    float* memK = buf2;               // memV at buf3 (mode-2 which*A)

    // split-bf16 encoder weights (hi/lo shorts) after the 5 fp32 regions
    short* sw = (short*)(ws + 5 * A);
    const int n_in_w  = DD * DIN;         // 131072
    const int n_qkv   = 3 * DD * DD;      // 786432
    const int n_out   = DD * DD;          // 262144
    const int n_ff1   = DFF * DD;         // 1048576
    const int n_ff2   = DD * DFF;         // 1048576
    const int n_mkv   = 2 * DD * DD;      // 524288
    const int n_wout  = DD * DD;          // 262144
    short* win_h  = sw;               short* win_l  = win_h  + n_in_w;
    short* eqkv_h = win_l  + n_in_w;  short* eqkv_l = eqkv_h + n_qkv;
    short* eout_h = eqkv_l + n_qkv;   short* eout_l = eout_h + n_out;
    short* eff1_h = eout_l + n_out;   short* eff1_l = eff1_h + n_ff1;
    short* eff2_h = eff1_l + n_ff1;   short* eff2_l = eff2_h + n_ff2;
    short* mkv_h  = eff2_l + n_ff2;   short* mkv_l  = mkv_h  + n_mkv;
    short* wout_h = mkv_l  + n_mkv;   short* wout_l = wout_h + n_wout;

    // decode smalls live inside buf4 (free after encoder FFN)
    float* db     = buf4;
    float* tgt    = db;                      // 557056
    float* kcache = tgt + BH17;
    float* vcache = kcache + BH17;
    float* qbuf   = vcache + BH17;           // 32768 each below
    float* sao    = qbuf + 32768;
    float* upre   = sao + 32768;
    float* u      = upre + 32768;
    float* caq    = u + 32768;
    float* cao    = caq + 32768;
    float* u2pre  = cao + 32768;
    float* u2     = u2pre + 32768;
    float* ffact  = u2 + 32768;              // 131072
    float* fpre   = ffact + 131072;          // 32768
    float* packed = fpre + 32768;            // 524288

    auto wconv = [&](const float* Wp, short* hp, short* lp, int n) {
        wconv_k<<<(n / 4 + 255) / 256, 256, 0, stream>>>(Wp, hp, lp, n / 4);
    };
    auto mgemm = [&](const float* Ap, int lda, const short* hp, const short* lp,
                     const float* bp, float* outp, int M, int N, int K, int mode) {
        dim3 g((M + 127) / 128, N / 128);
        mgemm_k<<<g, 256, 0, stream>>>(Ap, lda, hp, lp, bp, outp, M, N, K, mode);
    };
    auto ln = [&](const float* xp, const float* rp,
                  const float* g1, const float* b1, const float* g2, const float* b2,
                  float* op, int nrows, int dbl) {
        ln_k<<<(nrows + 3) / 4, 256, 0, stream>>>(xp, rp, g1, b1, g2, b2, op, nrows, dbl);
    };
    auto dmm = [&](const float* xp, long xs, const float* Wp, const float* bp,
                   const float* resp, long rs, float* outp,
                   float* kcp, float* vcp, int t, int N, int K, int mode) {
        dmm_k<<<N / 16, 256, 0, stream>>>(xp, xs, Wp, bp, resp, rs, outp, kcp, vcp, t, N, K, mode);
    };

    const int MS = BB * SS;  // 16384

    // ---- Weight splits (graph-safe, every call) ----
    wconv(W_in, win_h, win_l, n_in_w);
    wconv(enc_qkv_w, eqkv_h, eqkv_l, n_qkv);
    wconv(enc_out_w, eout_h, eout_l, n_out);
    wconv(enc_ff1_w, eff1_h, eff1_l, n_ff1);
    wconv(enc_ff2_w, eff2_h, eff2_l, n_ff2);
    wconv(dca_qkv_w + 512 * 512, mkv_h, mkv_l, n_mkv);
    wconv(W_out, wout_h, wout_l, n_wout);

    // ---- Encoder (split-bf16 MFMA GEMMs) ----
    mgemm(x, DIN, win_h, win_l, b_in, src, MS, DD, DIN, 0);
    mgemm(src, DD, eqkv_h, eqkv_l, enc_qkv_b, qh, MS, 3 * DD, DD, 2);
    enc_attn_k<<<BB * NH, 256, 0, stream>>>(buf1, buf2, buf3, attn);
    mgemm(attn, DD, eout_h, eout_l, enc_out_b, tmp, MS, DD, DD, 0);
    ln(tmp, src, enc_ln1_g, enc_ln1_b, nullptr, nullptr, h1, MS, 0);
    for (int c = 0; c < 2; ++c) {
        int roff = c * (MS / 2);
        mgemm(h1 + (long)roff * DD, DD, eff1_h, eff1_l, enc_ff1_b, ffbuf, MS / 2, DFF, DD, 1);
        mgemm(ffbuf, DFF, eff2_h, eff2_l, enc_ff2_b, tmp2 + (long)roff * DD, MS / 2, DD, DFF, 0);
    }
    ln(tmp2, h1, enc_ln2_g, enc_ln2_b, enc_norm_g, enc_norm_b, mem, MS, 1);
    mgemm(mem, DD, mkv_h, mkv_l, dca_qkv_b + 512, memK, MS, 2 * DD, DD, 2);

    // ---- Decoder (KV-cached, weight-broadcast dmm) ----
    init_tgt_k<<<(BB * DD + 255) / 256, 256, 0, stream>>>(start_tok, tgt);

    for (int t = 0; t < TLEN; ++t) {
        dmm(tgt + (long)t * DD, (long)TCAP * DD, dsa_qkv_w, dsa_qkv_b,
            nullptr, 0, qbuf, kcache, vcache, t, 3 * DD, DD, 2);
        dec_sa_k<<<BB * NH, 64, 0, stream>>>(qbuf, kcache, vcache, sao, t);
        dmm(sao, DD, dsa_out_w, dsa_out_b,
            tgt + (long)t * DD, (long)TCAP * DD, upre, nullptr, nullptr, 0, DD, DD, 0);
        dln_k<<<16, 256, 0, stream>>>(upre, DD, dln1_g, dln1_b, nullptr, nullptr, u, DD, 0);
        dmm(u, DD, dca_qkv_w, dca_qkv_b, nullptr, 0, caq, nullptr, nullptr, 0, DD, DD, 0);
        dec_ca_k<<<BB * NH, 256, 0, stream>>>(caq, memK, memK + A, cao);
        dmm(cao, DD, dca_out_w, dca_out_b, u, DD, u2pre, nullptr, nullptr, 0, DD, DD, 0);
        dln_k<<<16, 256, 0, stream>>>(u2pre, DD, dln2_g, dln2_b, nullptr, nullptr, u2, DD, 0);
        dmm(u2, DD, dff1_w, dff1_b, nullptr, 0, ffact, nullptr, nullptr, 0, DFF, DD, 1);
        dmm(ffact, DFF, dff2_w, dff2_b, u2, DD, fpre, nullptr, nullptr, 0, DD, DFF, 0);
        dln_k<<<16, 256, 0, stream>>>(fpre, DD, dln3_g, dln3_b, dnorm_g, dnorm_b,
                                      tgt + (long)(t + 1) * DD, (long)TCAP * DD, 1);
    }

    // ---- Output projection ----
    pack_k<<<(BB * TLEN * DD + 255) / 256, 256, 0, stream>>>(tgt, packed);
    mgemm(packed, DD, wout_h, wout_l, b_out, (float*)d_out, BB * TLEN, DD, DD, 0);
}